// Round 4
// baseline (29087.906 us; speedup 1.0000x reference)
//
#include <hip/hip_runtime.h>
#include <math.h>

// Problem constants (match reference)
#define BB   32
#define LSEQ 512
#define DD   512
#define HH   512
#define G2H  1024
#define K3H  1536

// Scan: 8 groups x 64 WGs. Group g owns batch rows 4g..4g+3. WG slot s owns
// c/innov/K cols jz=8s..8s+7 and kmid cols jm=24s..24s+23. WG = 256 thr =
// 4 waves; wave q owns col pair (2 c-cols / 6 kmid-cols) x all 4 rows.
//
// R4: tagged dataflow (R2/R3-proven protocol) with RUNTIME-VERIFIED
// XCD-LOCAL communication. If all 64 WGs of a group sit on one XCD
// (blk&7 under round-robin dispatch => 32 CUs = 1 XCD), comm ops use
// sc0-only (L1-bypass, XCD L2 = coherence point, ~300cy RTT) instead of
// sc1 (fabric/MALL, ~2-3us RTT). A 2-round sc0 ping-pong probe verifies
// BOTH placement and repeated-read freshness (round 2 catches sticky-L1);
// the group decision is made uniform via the proven sc1 master-aggregated
// barrier. Fallback = sc1 everywhere (correct, R3-speed + sleep backoff).
//
// Tagged word: u32 = (gen<<16) | f16bits(value). Dword atomicity only.
// Overwrite safety: 2 phases of transitive slack (R2 derivation).
// Stale-cache safety across layers: epilogue re-zeroes every owned tagged
// word (value == host memset value, so dirty-L2 / MALL / memset interleaving
// is benign in every combination); probe words are layer-epoch'd.
// CO-RESIDENCY required: LDS 76KB -> 2 WG/CU; all 512 WGs resident.
// HANG GUARD: bounded tag polls; exhaustion exits the poll only (phase
// structure preserved) -> fast garbage fail, never a hang.
#define NG   8
#define GWG  64
#define FPAD 16

// flag-region word offsets (per-group subranges inside)
#define OFF_A1 0
#define OFF_G1 (NG * GWG * FPAD)                  // 8192
#define OFF_A2 (OFF_G1 + NG * FPAD)               // 8320
#define OFF_G2 (OFF_A2 + NG * GWG * FPAD)         // 16512
#define OFF_PB (OFF_G2 + NG * FPAD)               // 16640
#define OFF_END (OFF_PB + NG * GWG * FPAD)        // 24832

typedef unsigned int u32;
typedef _Float16 half2_t __attribute__((ext_vector_type(2)));
typedef u32 v4u __attribute__((ext_vector_type(4)));

template<bool B> struct BC { static constexpr bool v = B; };

// ---- scope-templated comm ops --------------------------------------------
template<bool SYS>
__device__ __forceinline__ void tload4(v4u& d, const u32* p) {
  if constexpr (SYS)
    asm volatile("global_load_dwordx4 %0, %1, off sc1" : "=v"(d) : "v"(p));
  else
    asm volatile("global_load_dwordx4 %0, %1, off sc0" : "=v"(d) : "v"(p));
}
template<bool SYS>
__device__ __forceinline__ void tstore(u32* p, u32 v) {
  if constexpr (SYS)
    asm volatile("global_store_dword %0, %1, off sc0 sc1" :: "v"(p), "v"(v)
                 : "memory");
  else
    asm volatile("global_store_dword %0, %1, off sc0" :: "v"(p), "v"(v)
                 : "memory");
}
// Wait all outstanding vmem; sched_barrier so tag checks can't be hoisted
// above the wait (rule #18).
__device__ __forceinline__ void vmwait0() {
  asm volatile("s_waitcnt vmcnt(0)" ::: "memory");
  __builtin_amdgcn_sched_barrier(0);
}
// single-word load+wait (flag / probe polls) — wait fused into the asm so
// ordering is correct by construction
template<bool SYS>
__device__ __forceinline__ u32 tpoll(const u32* p) {
  u32 v;
  if constexpr (SYS)
    asm volatile("global_load_dword %0, %1, off sc1\n\ts_waitcnt vmcnt(0)"
                 : "=v"(v) : "v"(p) : "memory");
  else
    asm volatile("global_load_dword %0, %1, off sc0\n\ts_waitcnt vmcnt(0)"
                 : "=v"(v) : "v"(p) : "memory");
  __builtin_amdgcn_sched_barrier(0);
  return v;
}

__device__ __forceinline__ float dot2acc(u32 a, u32 b, float acc) {
#if __has_builtin(__builtin_amdgcn_fdot2)
  return __builtin_amdgcn_fdot2(__builtin_bit_cast(half2_t, a),
                                __builtin_bit_cast(half2_t, b), acc, false);
#else
  half2_t ha = __builtin_bit_cast(half2_t, a);
  half2_t hb = __builtin_bit_cast(half2_t, b);
  return acc + (float)ha[0] * (float)hb[0] + (float)ha[1] * (float)hb[1];
#endif
}
__device__ __forceinline__ float dotq(v4u a, v4u b, float acc) {
  acc = dot2acc(a.x, b.x, acc);
  acc = dot2acc(a.y, b.y, acc);
  acc = dot2acc(a.z, b.z, acc);
  acc = dot2acc(a.w, b.w, acc);
  return acc;
}
__device__ __forceinline__ u32 pkf16(float a, float b) {
#if __has_builtin(__builtin_amdgcn_cvt_pkrtz)
  return __builtin_bit_cast(u32, __builtin_amdgcn_cvt_pkrtz(a, b));
#else
  half2_t h; h[0] = (_Float16)a; h[1] = (_Float16)b;
  return __builtin_bit_cast(u32, h);
#endif
}

// tagged-word helpers -------------------------------------------------------
__device__ __forceinline__ u32 pairw(u32 lo, u32 hi) {
  return (lo & 0xffffu) | (hi << 16);
}
__device__ __forceinline__ v4u packpairs(v4u a, v4u b) {
  v4u r;
  r.x = pairw(a.x, a.y); r.y = pairw(a.z, a.w);
  r.z = pairw(b.x, b.y); r.w = pairw(b.z, b.w);
  return r;
}
__device__ __forceinline__ u32 tagx(v4u w, u32 genw) {
  return (w.x ^ genw) | (w.y ^ genw) | (w.z ^ genw) | (w.w ^ genw);
}

// In-register shuffle reduction trees (value for index lane&(M-1)).
template<int M> struct TreeC {
  static __device__ __forceinline__ void run(float* a, int lane, int d) {
    const bool hi = (lane & d) != 0;
#pragma unroll
    for (int i = 0; i < M / 2; ++i) {
      float mine  = hi ? a[2 * i + 1] : a[2 * i];
      float yours = hi ? a[2 * i]     : a[2 * i + 1];
      a[i] = mine + __shfl_xor(yours, d, 64);
    }
    TreeC<M / 2>::run(a, lane, d << 1);
  }
};
template<> struct TreeC<1> {
  static __device__ __forceinline__ void run(float*, int, int) {}
};
template<int M>
__device__ __forceinline__ float tree_reduce(float* a, int lane) {
  TreeC<M>::run(a, lane, 1);
  float v = a[0];
#pragma unroll
  for (int d = M; d <= 32; d <<= 1) v += __shfl_xor(v, d, 64);
  return v;
}

// ---------------------------------------------------------------------------
// RMSNorm: one 256-thread WG per row of 512.
// ---------------------------------------------------------------------------
__global__ __launch_bounds__(256)
void rmsnorm_kernel(const float* __restrict__ x, const float* __restrict__ w,
                    float* __restrict__ y)
{
  __shared__ float redl[256];
  const long row = blockIdx.x;
  const int t = threadIdx.x;
  const float* xr = x + row * DD;
  float v0 = xr[t], v1 = xr[t + 256];
  redl[t] = v0 * v0 + v1 * v1;
  __syncthreads();
  for (int off = 128; off > 0; off >>= 1) {
    if (t < off) redl[t] += redl[t + off];
    __syncthreads();
  }
  float scale = rsqrtf(redl[0] * (1.0f / 512.0f) + 1e-5f);
  float* yr = y + row * DD;
  yr[t]       = v0 * scale * w[t];
  yr[t + 256] = v1 * scale * w[t + 256];
}

// ---------------------------------------------------------------------------
// fp32 tiled GEMM: C[M,N] = A[M,K] @ B[K,N] (+ bias[n]), all row-major.
// ---------------------------------------------------------------------------
__global__ __launch_bounds__(256)
void gemm_fp32(const float* __restrict__ A, const float* __restrict__ B,
               const float* __restrict__ bias, float* __restrict__ C,
               int M, int N, int K)
{
  __shared__ float As[16][68];
  __shared__ float Bs[16][64];
  const int t  = threadIdx.x;
  const int tx = t & 15, ty = t >> 4;
  const long m0 = (long)blockIdx.x * 64;
  const long n0 = (long)blockIdx.y * 64;
  const int ar = t >> 2, ac = (t & 3) * 4;
  const int bk = t >> 4, bn = (t & 15) * 4;
  float acc[4][4] = {{0.f}};

  for (int k0 = 0; k0 < K; k0 += 16) {
    float4 av = *(const float4*)(A + (m0 + ar) * K + k0 + ac);
    float4 bv = *(const float4*)(B + (long)(k0 + bk) * N + n0 + bn);
    As[ac + 0][ar] = av.x; As[ac + 1][ar] = av.y;
    As[ac + 2][ar] = av.z; As[ac + 3][ar] = av.w;
    *(float4*)&Bs[bk][bn] = bv;
    __syncthreads();
#pragma unroll
    for (int kk = 0; kk < 16; ++kk) {
      float4 a = *(const float4*)&As[kk][ty * 4];
      float4 b = *(const float4*)&Bs[kk][tx * 4];
      acc[0][0] = fmaf(a.x, b.x, acc[0][0]); acc[0][1] = fmaf(a.x, b.y, acc[0][1]);
      acc[0][2] = fmaf(a.x, b.z, acc[0][2]); acc[0][3] = fmaf(a.x, b.w, acc[0][3]);
      acc[1][0] = fmaf(a.y, b.x, acc[1][0]); acc[1][1] = fmaf(a.y, b.y, acc[1][1]);
      acc[1][2] = fmaf(a.y, b.z, acc[1][2]); acc[1][3] = fmaf(a.y, b.w, acc[1][3]);
      acc[2][0] = fmaf(a.z, b.x, acc[2][0]); acc[2][1] = fmaf(a.z, b.y, acc[2][1]);
      acc[2][2] = fmaf(a.z, b.z, acc[2][2]); acc[2][3] = fmaf(a.z, b.w, acc[2][3]);
      acc[3][0] = fmaf(a.w, b.x, acc[3][0]); acc[3][1] = fmaf(a.w, b.y, acc[3][1]);
      acc[3][2] = fmaf(a.w, b.z, acc[3][2]); acc[3][3] = fmaf(a.w, b.w, acc[3][3]);
    }
    __syncthreads();
  }
  float4 bb = make_float4(0.f, 0.f, 0.f, 0.f);
  if (bias) bb = *(const float4*)(bias + n0 + tx * 4);
#pragma unroll
  for (int i = 0; i < 4; ++i) {
    float4 o;
    o.x = acc[i][0] + bb.x; o.y = acc[i][1] + bb.y;
    o.z = acc[i][2] + bb.z; o.w = acc[i][3] + bb.w;
    *(float4*)(C + (m0 + ty * 4 + i) * N + n0 + tx * 4) = o;
  }
}

// ---------------------------------------------------------------------------
// Persistent scan: 512 WGs x 256 thr, 76 KB static LDS.
// Tagged arrays (u32 = gen<<16 | f16):
//   tc[32][512]   c values  (written S3 tag it+1, read S1 tag it)
//   ti[32][512]   innov     (written S1 tag it+1, read S2 tag it+1)
//   tkk[32][1536] kmid      (written S2 tag it+1, read S3 tag it+1)
// Wave q polls row (4g+q) only; payload broadcast via LDS bc[].
// ---------------------------------------------------------------------------
__global__ __launch_bounds__(256, 2)
void scan_kernel(const float* __restrict__ gx,
                 const float* __restrict__ Whh, const float* __restrict__ bhh,
                 const float* __restrict__ loglam,
                 const float* __restrict__ kW1, const float* __restrict__ kb1,
                 const float* __restrict__ kW2, const float* __restrict__ kb2,
                 u32* __restrict__ tc, u32* __restrict__ ti,
                 u32* __restrict__ tkk, u32* __restrict__ flags,
                 float* __restrict__ hs, int layer)
{
  const int blk  = blockIdx.x;
  const int g    = blk & 7;         // group (rows 4g..4g+3)
  const int s    = blk >> 3;        // slot 0..63
  const int tid  = threadIdx.x;
  const int q    = tid >> 6;        // wave 0..3
  const int lane = tid & 63;
  const int jz   = s * 8;
  const int jm   = s * 24;

  __shared__ u32 wh[16 * 256];      // 16 KB: 8 z-cols + 8 m-cols, f16 pairs
  __shared__ u32 w1s[24 * 256];     // 24 KB
  __shared__ u32 w2s[8 * 768];      // 24 KB
  __shared__ u32 bc[4 * 768];       // 12 KB broadcast buffer (total 76 KB)
  __shared__ u32 decs;

  // ---- one-time weight staging (fp32 -> f16 pairs; pair p <-> k=2p,2p+1) ----
  for (int idx = tid; idx < 16 * 256; idx += 256) {
    int c = idx >> 8, p = idx & 255;
    int gcol = (c < 8) ? (jz + c) : (512 + jz + (c - 8));
    wh[idx] = pkf16(Whh[(size_t)(2 * p) * G2H + gcol],
                    Whh[(size_t)(2 * p + 1) * G2H + gcol]);
  }
  for (int idx = tid; idx < 24 * 256; idx += 256) {
    int c = idx >> 8, p = idx & 255;
    w1s[idx] = pkf16(kW1[(size_t)(2 * p) * K3H + jm + c],
                     kW1[(size_t)(2 * p + 1) * K3H + jm + c]);
  }
  for (int idx = tid; idx < 8 * 768; idx += 256) {
    int c = idx / 768, p = idx - c * 768;
    w2s[idx] = pkf16(kW2[(size_t)(2 * p) * HH + jz + c],
                     kW2[(size_t)(2 * p + 1) * HH + jz + c]);
  }
  __syncthreads();   // weights visible

  // per-lane constants (state mapping: r=(lane>>1)&3, ci=lane&1, lanes<8)
  const int colA = jz + 2 * q + (lane & 1);
  const float Ab   = 1.f - expf(loglam[colA]);
  const float bz   = bhh[colA];
  const float bm   = bhh[512 + colA];
  const float kb2c = kb2[colA];
  int kb1i = lane & 7; if (kb1i > 5) kb1i = 5;
  const float kb1v = kb1[jm + 6 * q + kb1i];

  const int r_st  = (lane >> 1) & 3;
  const int growst = 4 * g + r_st;
  const size_t hsoff = (size_t)growst * LSEQ * HH + colA;
  const size_t gxoff = (size_t)growst * LSEQ * G2H + colA;

  // slice pointers: wave q polls batch-row 4g+q, lane covers cols 8L..8L+7
  const u32* tcs = tc  + (size_t)(4 * g + q) * 512  + lane * 8;
  const u32* tis = ti  + (size_t)(4 * g + q) * 512  + lane * 8;
  const u32* tks = tkk + (size_t)(4 * g + q) * 1536 + lane * 8;

  u32* tiw = ti + (size_t)growst * 512 + colA;      // lanes<8
  u32* tcw = tc + (size_t)growst * 512 + colA;      // lanes<8
  const int rr = (lane >> 3) & 3, cc = lane & 7;    // S2 store map (lanes<32)
  u32* tkw = tkk + (size_t)(4 * g + rr) * 1536 + jm + 6 * q + cc;

  // ---- runtime scope probe: group XCD-locality + sc0 repeated-read ----
  u32* pbg = flags + OFF_PB + (size_t)g * GWG * FPAD;
  const u32 e1 = ((u32)layer << 4) + 1u, e2 = e1 + 1u;
  if (tid == 0) tstore<false>(pbg + s * FPAD, e1);
  u32 myval = 1;
  if (tid < 64) {                       // wave 0: lane L polls slot L
    const u32* ap = pbg + tid * FPAD;
    int succ1 = 0, succ2 = 0;
    for (int b = 0; b < 1024; ++b)
      if (tpoll<false>(ap) >= e1) { succ1 = 1; break; }
    if (tid == 0) tstore<false>(pbg + s * FPAD, e2);   // round 2 ping
    for (int b = 0; b < 1024; ++b)
      if (tpoll<false>(ap) >= e2) { succ2 = 1; break; }
    unsigned long long bb = __ballot(succ1 && succ2);
    if (tid == 0) myval = (bb == ~0ull) ? 2u : 1u;
  }

  // ---- group-uniform decision via proven sc1 master-aggregated barrier ----
  {
    u32* arr = flags + OFF_A1 + (size_t)g * GWG * FPAD;
    u32* go  = flags + OFF_G1 + (size_t)g * FPAD;
    __syncthreads();                    // drain probe stores
    if (s == 0) {
      if (tid < 64) {
        u32 v = myval;
        if (tid >= 1) {
          const u32* ap = arr + tid * FPAD;
          do { v = tpoll<true>(ap); } while (v == 0);
        }
        unsigned long long bb = __ballot(v == 2u);
        if (tid == 0) tstore<true>(go, bb == ~0ull ? 2u : 1u);
      }
    } else {
      if (tid == 0) tstore<true>(arr + s * FPAD, myval);
    }
    if (tid == 0) {
      u32 v;
      do { v = tpoll<true>(go); } while (v == 0);
      decs = v;
    }
    __syncthreads();
  }
  const bool fastp = (decs == 2u);

  // ---- main loop (scope-templated via generic lambda) ----------------------
  auto loop = [&](auto sysc) {
    constexpr bool SYS = decltype(sysc)::v;
    float A_own = 0.f, c_own = 0.f, M_own = 0.f, I_own = 0.f, s_own = 1.f;
    int spin = 1 << 22;   // hang guard

    for (int it = 0; it <= LSEQ; ++it) {
      const u32 genc = ((u32)it) << 16;
      const u32 genn = ((u32)(it + 1)) << 16;

      float gxz = 0.f, gxm = 0.f;
      if (lane < 8 && it < LSEQ) {
        gxz = gx[gxoff + (size_t)it * G2H];
        gxm = gx[gxoff + (size_t)it * G2H + 512];
      }

      // ---- S1: wave q polls c(it) row q ----
      {
        v4u w0, w1;
        for (;;) {
          tload4<SYS>(w0, tcs); tload4<SYS>(w1, tcs + 4);
          vmwait0();
          u32 d = tagx(w0, genc) | tagx(w1, genc);
          if (__all((d & 0xffff0000u) == 0)) break;
          if (--spin < 0) break;
          if constexpr (SYS) __builtin_amdgcn_s_sleep(2);
        }
        *(v4u*)(bc + q * 256 + lane * 4) = packpairs(w0, w1);
      }
      __syncthreads();
      v4u cv[4];
#pragma unroll
      for (int r = 0; r < 4; ++r) cv[r] = *(const v4u*)(bc + r * 256 + lane * 4);

      float a4[4] = { dotq(cv[0], cv[0], 0.f), dotq(cv[1], cv[1], 0.f),
                      dotq(cv[2], cv[2], 0.f), dotq(cv[3], cv[3], 0.f) };
      float a16[16];
#pragma unroll
      for (int t = 0; t < 4; ++t) {        // t<2: z col 2q+t ; t>=2: m col
        int col = (t < 2) ? (2 * q + t) : (8 + 2 * q + (t - 2));
        v4u wq = *(const v4u*)(wh + col * 256 + lane * 4);
        a16[0 * 4 + t] = dotq(cv[0], wq, 0.f);
        a16[1 * 4 + t] = dotq(cv[1], wq, 0.f);
        a16[2 * 4 + t] = dotq(cv[2], wq, 0.f);
        a16[3 * 4 + t] = dotq(cv[3], wq, 0.f);
      }
      float ssv = tree_reduce<4>(a4, lane);     // row = lane&3
      float g16 = tree_reduce<16>(a16, lane);   // (r=(lane&15)>>2, t=lane&3)
      float sq  = __shfl(ssv, r_st, 64);
      float s_loc = fminf(1.f, 10.f * rsqrtf(sq + 1e-6f));
      float gz = __shfl(g16, (r_st * 4 + (lane & 1)) & 63, 64);
      float gm = __shfl(g16, (r_st * 4 + 2 + (lane & 1)) & 63, 64);
      if (lane < 8 && it >= 1)
        hs[hsoff + (size_t)(it - 1) * HH] = s_loc * c_own;
      if (it == LSEQ) break;              // uniform across all waves/WGs
      float gzv = gz * s_loc + gxz + bz;
      float gmv = gm * s_loc + gxm + bm;
      float Mv = tanhf(gmv);
      float ivf = gzv - A_own * (s_loc * c_own) - Mv;
      if (lane < 8) {
        M_own = Mv; I_own = ivf; s_own = s_loc;
        tstore<SYS>(tiw, genn | pkf16(ivf, 0.f));
      }
      __syncthreads();                    // all waves done reading bc (S1)

      // ---- S2: wave q polls innov(it+1) row q ----
      {
        v4u w0, w1;
        for (;;) {
          tload4<SYS>(w0, tis); tload4<SYS>(w1, tis + 4);
          vmwait0();
          u32 d = tagx(w0, genn) | tagx(w1, genn);
          if (__all((d & 0xffff0000u) == 0)) break;
          if (--spin < 0) break;
          if constexpr (SYS) __builtin_amdgcn_s_sleep(2);
        }
        *(v4u*)(bc + q * 256 + lane * 4) = packpairs(w0, w1);
      }
      __syncthreads();
      v4u pv[4];
#pragma unroll
      for (int r = 0; r < 4; ++r) pv[r] = *(const v4u*)(bc + r * 256 + lane * 4);

      float a32[32];
#pragma unroll
      for (int i = 0; i < 32; ++i) a32[i] = 0.f;
#pragma unroll
      for (int cj = 0; cj < 6; ++cj) {
        v4u wq = *(const v4u*)(w1s + (6 * q + cj) * 256 + lane * 4);
        a32[0 * 8 + cj] = dotq(pv[0], wq, 0.f);
        a32[1 * 8 + cj] = dotq(pv[1], wq, 0.f);
        a32[2 * 8 + cj] = dotq(pv[2], wq, 0.f);
        a32[3 * 8 + cj] = dotq(pv[3], wq, 0.f);
      }
      float t32 = tree_reduce<32>(a32, lane);   // (r=(lane&31)>>3, cc=lane&7)
      float kvb = t32 + kb1v;
      float gl = 0.5f * kvb * (1.f + erff(kvb * 0.7071067811865476f));
      if (lane < 32 && cc < 6)
        tstore<SYS>(tkw, genn | pkf16(gl, 0.f));
      __syncthreads();                    // all waves done reading bc (S2)

      // ---- S3: wave q polls kmid(it+1) row q ----
      {
        v4u w0, w1, w2, w3, w4, w5;
        for (;;) {
          tload4<SYS>(w0, tks);        tload4<SYS>(w1, tks + 4);
          tload4<SYS>(w2, tks + 512);  tload4<SYS>(w3, tks + 516);
          tload4<SYS>(w4, tks + 1024); tload4<SYS>(w5, tks + 1028);
          vmwait0();
          u32 d = tagx(w0, genn) | tagx(w1, genn) | tagx(w2, genn) |
                  tagx(w3, genn) | tagx(w4, genn) | tagx(w5, genn);
          if (__all((d & 0xffff0000u) == 0)) break;
          if (--spin < 0) break;
          if constexpr (SYS) __builtin_amdgcn_s_sleep(2);
        }
        *(v4u*)(bc + q * 768 +   0 + lane * 4) = packpairs(w0, w1);
        *(v4u*)(bc + q * 768 + 256 + lane * 4) = packpairs(w2, w3);
        *(v4u*)(bc + q * 768 + 512 + lane * 4) = packpairs(w4, w5);
      }
      __syncthreads();
      float a8[8];
#pragma unroll
      for (int ci = 0; ci < 2; ++ci) {
        const u32* wc = w2s + (2 * q + ci) * 768 + lane * 4;
        v4u wq0 = *(const v4u*)(wc);
        v4u wq1 = *(const v4u*)(wc + 256);
        v4u wq2 = *(const v4u*)(wc + 512);
#pragma unroll
        for (int r = 0; r < 4; ++r) {
          v4u k0 = *(const v4u*)(bc + r * 768 +   0 + lane * 4);
          v4u k1 = *(const v4u*)(bc + r * 768 + 256 + lane * 4);
          v4u k2 = *(const v4u*)(bc + r * 768 + 512 + lane * 4);
          a8[r * 2 + ci] = dotq(k2, wq2, dotq(k1, wq1, dotq(k0, wq0, 0.f)));
        }
      }
      float krd = tree_reduce<8>(a8, lane);   // (r=(lane&7)>>1, ci=lane&1)
      float Kv = tanhf(krd + kb2c) * 0.5f;
      float An = Ab * (1.f - Kv * Kv);
      float cn = An * (s_own * c_own) + Kv * I_own + M_own;
      if (lane < 8) {
        A_own = An; c_own = cn;
        tstore<SYS>(tcw, genn | pkf16(cn, 0.f));
      }
      __syncthreads();                    // all waves done reading bc (S3)
    }
  };
  if (fastp) loop(BC<false>{});
  else       loop(BC<true>{});

  // ---- epilogue: group barrier, then re-zero owned tagged words so no
  //      stale tags survive in ANY cache level (value == host memset) ----
  {
    u32* arr = flags + OFF_A2 + (size_t)g * GWG * FPAD;
    u32* go  = flags + OFF_G2 + (size_t)g * FPAD;
    __syncthreads();
    if (s == 0) {
      if (tid < 64) {
        u32 v = 1;
        if (tid >= 1) {
          const u32* ap = arr + tid * FPAD;
          do { v = tpoll<true>(ap); } while (v == 0);
        }
        if (tid == 0) tstore<true>(go, 1u);
      }
    } else {
      if (tid == 0) tstore<true>(arr + s * FPAD, 1u);
    }
    if (tid == 0) {
      u32 v;
      do { v = tpoll<true>(go); } while (v == 0);
    }
    __syncthreads();
  }
  if (fastp) {
    if (lane < 8) { tstore<false>(tcw, 0u); tstore<false>(tiw, 0u); }
    if (lane < 32 && cc < 6) tstore<false>(tkw, 0u);
  } else {
    if (lane < 8) { tstore<true>(tcw, 0u); tstore<true>(tiw, 0u); }
    if (lane < 32 && cc < 6) tstore<true>(tkw, 0u);
  }
}

// ---------------------------------------------------------------------------
// Workspace layout (bytes):
//   [0, 32M)    xn (reused as hs)
//   [32M, 96M)  gx
//   [96M,128M)  xmid
//   [128M, ..)  tc 64K | ti 64K | tkk 192K | flags ~100K
// ---------------------------------------------------------------------------
extern "C" void kernel_launch(void* const* d_in, const int* in_sizes, int n_in,
                              void* d_out, int out_size, void* d_ws, size_t ws_size,
                              hipStream_t stream) {
  const float* x      = (const float*)d_in[0];
  const float* norm_w = (const float*)d_in[1];
  const float* W_ih   = (const float*)d_in[2];
  const float* b_ih   = (const float*)d_in[3];
  const float* W_hh   = (const float*)d_in[4];
  const float* b_hh   = (const float*)d_in[5];
  const float* loglam = (const float*)d_in[6];
  const float* kW1    = (const float*)d_in[7];
  const float* kb1    = (const float*)d_in[8];
  const float* kW2    = (const float*)d_in[9];
  const float* kb2    = (const float*)d_in[10];
  const float* Wo     = (const float*)d_in[11];
  float* out = (float*)d_out;

  char* ws = (char*)d_ws;
  float* xn   = (float*)(ws);
  float* gxb  = (float*)(ws + (size_t)33554432);
  float* xmid = (float*)(ws + (size_t)100663296);
  u32* tc    = (u32*)(ws + (size_t)134217728);
  u32* ti    = tc + 16384;          // 32*512
  u32* tkk   = ti + 16384;          // 32*1536
  u32* flags = tkk + 49152;
  float* hs = xn;

  // memset covers tags + all flag/probe regions
  const size_t clr_bytes = (size_t)(16384 + 16384 + 49152 + OFF_END) * sizeof(u32);

  for (int l = 0; l < 2; ++l) {
    const float* xin = l ? (const float*)xmid : x;
    float* cout = l ? out : xmid;

    rmsnorm_kernel<<<BB * LSEQ, 256, 0, stream>>>(xin, norm_w, xn);

    gemm_fp32<<<dim3(256, 16), 256, 0, stream>>>(
        xn, W_ih + (size_t)l * DD * G2H, b_ih + (size_t)l * G2H, gxb,
        BB * LSEQ, G2H, DD);

    hipMemsetAsync(tc, 0, clr_bytes, stream);

    scan_kernel<<<NG * GWG, 256, 0, stream>>>(
        gxb,
        W_hh + (size_t)l * HH * G2H, b_hh + (size_t)l * G2H,
        loglam + (size_t)l * HH,
        kW1 + (size_t)l * HH * K3H, kb1 + (size_t)l * K3H,
        kW2 + (size_t)l * K3H * HH, kb2 + (size_t)l * HH,
        tc, ti, tkk, flags, hs, l);

    gemm_fp32<<<dim3(256, 8), 256, 0, stream>>>(
        hs, Wo + (size_t)l * HH * DD, nullptr, cout,
        BB * LSEQ, DD, HH);
  }
}

// Round 5
// 19511.415 us; speedup vs baseline: 1.4908x; 1.4908x over previous
//
#include <hip/hip_runtime.h>
#include <math.h>

// Problem constants (match reference)
#define BB   32
#define LSEQ 512
#define DD   512
#define HH   512
#define G2H  1024
#define K3H  1536

// Scan: 8 groups x 64 WGs (group = blk&7). Group g owns batch rows 4g..4g+3.
// WG slot s owns c/innov/K cols jz=8s..8s+7 and kmid cols jm=24s..24s+23.
// WG = 256 thr = 4 waves; wave q owns col pair (2 c-cols / 6 kmid-cols) x 4 rows.
//
// R5 = R0 (proven 3-barrier protocol, 10us/step) + two surgical changes:
//  (a) COOPERATIVE PAYLOAD READ: the WG's 256 threads fetch each phase's
//      4-row payload ONCE (contiguous region), bounce via 12KB LDS, all
//      4 waves compute from LDS. Cuts coherent gather 40->10 MB/step
//      (R0 had every wave re-load everything: 4x amplification).
//  (b) DISTRIBUTED BARRIER: each WG stores gen to arrive[s] (64 compact
//      words/group = 4 lines); wave 0 polls all 64 slots (ballot). Removes
//      the master->go hop (~1 RTT/phase of 3 phases/step).
// Data coherence: sc0+sc1 stores / sc1 loads through the memory-side cache,
// explicit vmcnt(0) drain before each barrier (R0-proven mechanism).
// CO-RESIDENCY: LDS 76KB + launch_bounds(256,2) => 2 WG/CU => all 512 WGs
// resident (R0/R3-proven at this footprint).
// HANG GUARD: bounded polls; exhaustion exits the poll only -> fast garbage
// fail, never a hang.
#define NG   8
#define GWG  64

typedef unsigned int u32;
typedef _Float16 half2_t __attribute__((ext_vector_type(2)));
typedef u32 v4u __attribute__((ext_vector_type(4)));

// ---- coherence-point memory ops (R0-proven) -------------------------------
__device__ __forceinline__ void mload4(v4u& d, const u32* p) {
  asm volatile("global_load_dwordx4 %0, %1, off sc1" : "=v"(d) : "v"(p));
}
__device__ __forceinline__ void vmwait0() {
  asm volatile("s_waitcnt vmcnt(0)" ::: "memory");
  __builtin_amdgcn_sched_barrier(0);
}
__device__ __forceinline__ void mstore(u32* p, u32 v) {
  asm volatile("global_store_dword %0, %1, off sc0 sc1" :: "v"(p), "v"(v)
               : "memory");
}
// fused load+wait for flag polls (ordering correct by construction)
__device__ __forceinline__ u32 tpoll(const u32* p) {
  u32 v;
  asm volatile("global_load_dword %0, %1, off sc1\n\ts_waitcnt vmcnt(0)"
               : "=v"(v) : "v"(p) : "memory");
  __builtin_amdgcn_sched_barrier(0);
  return v;
}

__device__ __forceinline__ float dot2acc(u32 a, u32 b, float acc) {
#if __has_builtin(__builtin_amdgcn_fdot2)
  return __builtin_amdgcn_fdot2(__builtin_bit_cast(half2_t, a),
                                __builtin_bit_cast(half2_t, b), acc, false);
#else
  half2_t ha = __builtin_bit_cast(half2_t, a);
  half2_t hb = __builtin_bit_cast(half2_t, b);
  return acc + (float)ha[0] * (float)hb[0] + (float)ha[1] * (float)hb[1];
#endif
}
__device__ __forceinline__ float dotq(v4u a, v4u b, float acc) {
  acc = dot2acc(a.x, b.x, acc);
  acc = dot2acc(a.y, b.y, acc);
  acc = dot2acc(a.z, b.z, acc);
  acc = dot2acc(a.w, b.w, acc);
  return acc;
}
__device__ __forceinline__ u32 pkf16(float a, float b) {
#if __has_builtin(__builtin_amdgcn_cvt_pkrtz)
  return __builtin_bit_cast(u32, __builtin_amdgcn_cvt_pkrtz(a, b));
#else
  half2_t h; h[0] = (_Float16)a; h[1] = (_Float16)b;
  return __builtin_bit_cast(u32, h);
#endif
}

// In-register shuffle reduction trees (value for index lane&(M-1)).
template<int M> struct TreeC {
  static __device__ __forceinline__ void run(float* a, int lane, int d) {
    const bool hi = (lane & d) != 0;
#pragma unroll
    for (int i = 0; i < M / 2; ++i) {
      float mine  = hi ? a[2 * i + 1] : a[2 * i];
      float yours = hi ? a[2 * i]     : a[2 * i + 1];
      a[i] = mine + __shfl_xor(yours, d, 64);
    }
    TreeC<M / 2>::run(a, lane, d << 1);
  }
};
template<> struct TreeC<1> {
  static __device__ __forceinline__ void run(float*, int, int) {}
};
template<int M>
__device__ __forceinline__ float tree_reduce(float* a, int lane) {
  TreeC<M>::run(a, lane, 1);
  float v = a[0];
#pragma unroll
  for (int d = M; d <= 32; d <<= 1) v += __shfl_xor(v, d, 64);
  return v;
}

// ---------------------------------------------------------------------------
// RMSNorm: one 256-thread WG per row of 512.
// ---------------------------------------------------------------------------
__global__ __launch_bounds__(256)
void rmsnorm_kernel(const float* __restrict__ x, const float* __restrict__ w,
                    float* __restrict__ y)
{
  __shared__ float redl[256];
  const long row = blockIdx.x;
  const int t = threadIdx.x;
  const float* xr = x + row * DD;
  float v0 = xr[t], v1 = xr[t + 256];
  redl[t] = v0 * v0 + v1 * v1;
  __syncthreads();
  for (int off = 128; off > 0; off >>= 1) {
    if (t < off) redl[t] += redl[t + off];
    __syncthreads();
  }
  float scale = rsqrtf(redl[0] * (1.0f / 512.0f) + 1e-5f);
  float* yr = y + row * DD;
  yr[t]       = v0 * scale * w[t];
  yr[t + 256] = v1 * scale * w[t + 256];
}

// ---------------------------------------------------------------------------
// fp32 tiled GEMM: C[M,N] = A[M,K] @ B[K,N] (+ bias[n]), all row-major.
// ---------------------------------------------------------------------------
__global__ __launch_bounds__(256)
void gemm_fp32(const float* __restrict__ A, const float* __restrict__ B,
               const float* __restrict__ bias, float* __restrict__ C,
               int M, int N, int K)
{
  __shared__ float As[16][68];
  __shared__ float Bs[16][64];
  const int t  = threadIdx.x;
  const int tx = t & 15, ty = t >> 4;
  const long m0 = (long)blockIdx.x * 64;
  const long n0 = (long)blockIdx.y * 64;
  const int ar = t >> 2, ac = (t & 3) * 4;
  const int bk = t >> 4, bn = (t & 15) * 4;
  float acc[4][4] = {{0.f}};

  for (int k0 = 0; k0 < K; k0 += 16) {
    float4 av = *(const float4*)(A + (m0 + ar) * K + k0 + ac);
    float4 bv = *(const float4*)(B + (long)(k0 + bk) * N + n0 + bn);
    As[ac + 0][ar] = av.x; As[ac + 1][ar] = av.y;
    As[ac + 2][ar] = av.z; As[ac + 3][ar] = av.w;
    *(float4*)&Bs[bk][bn] = bv;
    __syncthreads();
#pragma unroll
    for (int kk = 0; kk < 16; ++kk) {
      float4 a = *(const float4*)&As[kk][ty * 4];
      float4 b = *(const float4*)&Bs[kk][tx * 4];
      acc[0][0] = fmaf(a.x, b.x, acc[0][0]); acc[0][1] = fmaf(a.x, b.y, acc[0][1]);
      acc[0][2] = fmaf(a.x, b.z, acc[0][2]); acc[0][3] = fmaf(a.x, b.w, acc[0][3]);
      acc[1][0] = fmaf(a.y, b.x, acc[1][0]); acc[1][1] = fmaf(a.y, b.y, acc[1][1]);
      acc[1][2] = fmaf(a.y, b.z, acc[1][2]); acc[1][3] = fmaf(a.y, b.w, acc[1][3]);
      acc[2][0] = fmaf(a.z, b.x, acc[2][0]); acc[2][1] = fmaf(a.z, b.y, acc[2][1]);
      acc[2][2] = fmaf(a.z, b.z, acc[2][2]); acc[2][3] = fmaf(a.z, b.w, acc[2][3]);
      acc[3][0] = fmaf(a.w, b.x, acc[3][0]); acc[3][1] = fmaf(a.w, b.y, acc[3][1]);
      acc[3][2] = fmaf(a.w, b.z, acc[3][2]); acc[3][3] = fmaf(a.w, b.w, acc[3][3]);
    }
    __syncthreads();
  }
  float4 bb = make_float4(0.f, 0.f, 0.f, 0.f);
  if (bias) bb = *(const float4*)(bias + n0 + tx * 4);
#pragma unroll
  for (int i = 0; i < 4; ++i) {
    float4 o;
    o.x = acc[i][0] + bb.x; o.y = acc[i][1] + bb.y;
    o.z = acc[i][2] + bb.z; o.w = acc[i][3] + bb.w;
    *(float4*)(C + (m0 + ty * 4 + i) * N + n0 + tx * 4) = o;
  }
}

// ---------------------------------------------------------------------------
// Persistent scan: 512 WGs x 256 thr, 76 KB static LDS.
// Packed f16-pair comm arrays (R0 layout):
//   cpk[32][256]  c     (written S3, read S1 of next step)
//   ipk[32][256]  innov (written S1, read S2)
//   kpk[32][768]  kmid  (written S2, read S3)
// Distributed barrier flags: arrive[g][64] compact, group stride 128 words.
// ---------------------------------------------------------------------------
__global__ __launch_bounds__(256, 2)
void scan_kernel(const float* __restrict__ gx,
                 const float* __restrict__ Whh, const float* __restrict__ bhh,
                 const float* __restrict__ loglam,
                 const float* __restrict__ kW1, const float* __restrict__ kb1,
                 const float* __restrict__ kW2, const float* __restrict__ kb2,
                 u32* __restrict__ cpk, u32* __restrict__ ipk,
                 u32* __restrict__ kpk, u32* __restrict__ flags,
                 float* __restrict__ hs)
{
  const int blk  = blockIdx.x;
  const int g    = blk & 7;         // group (rows 4g..4g+3)
  const int s    = blk >> 3;        // slot 0..63
  const int tid  = threadIdx.x;
  const int q    = tid >> 6;        // wave 0..3
  const int lane = tid & 63;
  const int jz   = s * 8;
  const int jm   = s * 24;

  __shared__ u32 wh[16 * 256];      // 16 KB: 8 z-cols + 8 m-cols, f16 pairs
  __shared__ u32 w1s[24 * 256];     // 24 KB
  __shared__ u32 w2s[8 * 768];      // 24 KB
  __shared__ u32 bc[4 * 768];       // 12 KB payload bounce (total 76 KB)

  // ---- one-time weight staging (fp32 -> f16 pairs; pair p <-> k=2p,2p+1) ----
  for (int idx = tid; idx < 16 * 256; idx += 256) {
    int c = idx >> 8, p = idx & 255;
    int gcol = (c < 8) ? (jz + c) : (512 + jz + (c - 8));
    wh[idx] = pkf16(Whh[(size_t)(2 * p) * G2H + gcol],
                    Whh[(size_t)(2 * p + 1) * G2H + gcol]);
  }
  for (int idx = tid; idx < 24 * 256; idx += 256) {
    int c = idx >> 8, p = idx & 255;
    w1s[idx] = pkf16(kW1[(size_t)(2 * p) * K3H + jm + c],
                     kW1[(size_t)(2 * p + 1) * K3H + jm + c]);
  }
  for (int idx = tid; idx < 8 * 768; idx += 256) {
    int c = idx / 768, p = idx - c * 768;
    w2s[idx] = pkf16(kW2[(size_t)(2 * p) * HH + jz + c],
                     kW2[(size_t)(2 * p + 1) * HH + jz + c]);
  }
  __syncthreads();   // weights + bc usable

  // per-lane constants (state mapping: r=(lane>>1)&3, ci=lane&1, lanes<8)
  const int colA = jz + 2 * q + (lane & 1);
  const float Ab   = 1.f - expf(loglam[colA]);
  const float bz   = bhh[colA];
  const float bm   = bhh[512 + colA];
  const float kb2c = kb2[colA];
  int kb1i = lane & 7; if (kb1i > 5) kb1i = 5;
  const float kb1v = kb1[jm + 6 * q + kb1i];

  const int r_st  = (lane >> 1) & 3;
  const int growst = 4 * g + r_st;
  const size_t hsoff = (size_t)growst * LSEQ * HH + colA;
  const size_t gxoff = (size_t)growst * LSEQ * G2H + colA;

  // group-contiguous payload bases (rows 4g..4g+3)
  const u32* cg = cpk + (size_t)(4 * g) * 256;   // 1024 words
  const u32* ig = ipk + (size_t)(4 * g) * 256;   // 1024 words
  const u32* kg = kpk + (size_t)(4 * g) * 768;   // 3072 words

  // store pointers (R0 mapping)
  u32* ciw = ipk + (size_t)growst * 256 + 4 * s + q;               // lanes<8 even
  u32* ccw = cpk + (size_t)growst * 256 + 4 * s + q;               // lanes<8 even
  const int rr = (lane >> 3) & 3, cc = lane & 7;                   // S2 map
  u32* ckw = kpk + (size_t)(4 * g + rr) * 768 + 12 * s + 3 * q + (cc >> 1);

  u32* arr = flags + g * 128;       // 64 compact arrive words per group

  float A_own = 0.f, c_own = 0.f, M_own = 0.f, I_own = 0.f, s_own = 1.f;
  int spin = 1 << 20;               // hang guard
  u32 gen = 0;

  // distributed barrier: drain stores -> arrive -> wave0 polls all 64 slots
  auto xbar = [&](u32 gv) {
    vmwait0();                      // this WG's comm stores at coherence point
    __syncthreads();
    if (tid == 0) mstore(arr + s, gv);
    if (tid < 64) {
      for (;;) {
        u32 v = tpoll(arr + tid);
        if (__all((int)(v >= gv))) break;
        if (--spin < 0) break;
      }
    }
    __syncthreads();
  };

  for (int it = 0; it <= LSEQ; ++it) {
    // gx prefetch (cached, read-once)
    float gxz = 0.f, gxm = 0.f;
    if (lane < 8 && it < LSEQ) {
      gxz = gx[gxoff + (size_t)it * G2H];
      gxm = gx[gxoff + (size_t)it * G2H + 512];
    }

    // ---- S1: coop-load c(it) [1024 words], compute from LDS ----
    {
      v4u v;
      mload4(v, cg + tid * 4);
      vmwait0();
      *(v4u*)(bc + tid * 4) = v;
    }
    __syncthreads();
    v4u cv[4];
#pragma unroll
    for (int r = 0; r < 4; ++r) cv[r] = *(const v4u*)(bc + r * 256 + lane * 4);

    float a4[4] = { dotq(cv[0], cv[0], 0.f), dotq(cv[1], cv[1], 0.f),
                    dotq(cv[2], cv[2], 0.f), dotq(cv[3], cv[3], 0.f) };
    float a16[16];
#pragma unroll
    for (int t = 0; t < 4; ++t) {          // t<2: z col 2q+t ; t>=2: m col
      int col = (t < 2) ? (2 * q + t) : (8 + 2 * q + (t - 2));
      v4u wq = *(const v4u*)(wh + col * 256 + lane * 4);
      a16[0 * 4 + t] = dotq(cv[0], wq, 0.f);
      a16[1 * 4 + t] = dotq(cv[1], wq, 0.f);
      a16[2 * 4 + t] = dotq(cv[2], wq, 0.f);
      a16[3 * 4 + t] = dotq(cv[3], wq, 0.f);
    }
    float ssv = tree_reduce<4>(a4, lane);     // row = lane&3
    float g16 = tree_reduce<16>(a16, lane);   // (r=(lane&15)>>2, t=lane&3)
    float sq  = __shfl(ssv, r_st, 64);
    float s_loc = fminf(1.f, 10.f * rsqrtf(sq + 1e-6f));
    float gz = __shfl(g16, (r_st * 4 + (lane & 1)) & 63, 64);
    float gm = __shfl(g16, (r_st * 4 + 2 + (lane & 1)) & 63, 64);
    if (lane < 8 && it >= 1)
      hs[hsoff + (size_t)(it - 1) * HH] = s_loc * c_own;
    if (it == LSEQ) break;
    float gzv = gz * s_loc + gxz + bz;
    float gmv = gm * s_loc + gxm + bm;
    float Mv = tanhf(gmv);
    float iv = gzv - A_own * (s_loc * c_own) - Mv;
    if (lane < 8) { M_own = Mv; I_own = iv; s_own = s_loc; }
    float ivn = __shfl(iv, (lane + 1) & 63, 64);
    if (lane < 8 && !(lane & 1))
      mstore(ciw, pkf16(iv, ivn));
    xbar(++gen);

    // ---- S2: coop-load innov [1024 words], kmid = gelu(innov @ kW1) ----
    {
      v4u v;
      mload4(v, ig + tid * 4);
      vmwait0();
      *(v4u*)(bc + tid * 4) = v;
    }
    __syncthreads();
    v4u pv[4];
#pragma unroll
    for (int r = 0; r < 4; ++r) pv[r] = *(const v4u*)(bc + r * 256 + lane * 4);

    float a32[32];
#pragma unroll
    for (int i = 0; i < 32; ++i) a32[i] = 0.f;
#pragma unroll
    for (int cj = 0; cj < 6; ++cj) {
      v4u wq = *(const v4u*)(w1s + (6 * q + cj) * 256 + lane * 4);
      a32[0 * 8 + cj] = dotq(pv[0], wq, 0.f);
      a32[1 * 8 + cj] = dotq(pv[1], wq, 0.f);
      a32[2 * 8 + cj] = dotq(pv[2], wq, 0.f);
      a32[3 * 8 + cj] = dotq(pv[3], wq, 0.f);
    }
    float t32 = tree_reduce<32>(a32, lane);   // (r=(lane&31)>>3, cc=lane&7)
    float kvb = t32 + kb1v;
    float gl = 0.5f * kvb * (1.f + erff(kvb * 0.7071067811865476f));
    float gln = __shfl(gl, (lane + 1) & 63, 64);
    if (lane < 32 && !(lane & 1) && cc < 6)
      mstore(ckw, pkf16(gl, gln));
    xbar(++gen);

    // ---- S3: coop-load kmid [3072 words], K = tanh(kmid@kW2)*0.5 ; c ----
    {
      v4u v0, v1, v2;
      mload4(v0, kg + tid * 4);
      mload4(v1, kg + 1024 + tid * 4);
      mload4(v2, kg + 2048 + tid * 4);
      vmwait0();
      *(v4u*)(bc + tid * 4) = v0;
      *(v4u*)(bc + 1024 + tid * 4) = v1;
      *(v4u*)(bc + 2048 + tid * 4) = v2;
    }
    __syncthreads();
    float a8[8];
#pragma unroll
    for (int ci = 0; ci < 2; ++ci) {
      const u32* wc = w2s + (2 * q + ci) * 768 + lane * 4;
      v4u wq0 = *(const v4u*)(wc);
      v4u wq1 = *(const v4u*)(wc + 256);
      v4u wq2 = *(const v4u*)(wc + 512);
#pragma unroll
      for (int r = 0; r < 4; ++r) {
        v4u k0 = *(const v4u*)(bc + r * 768 +   0 + lane * 4);
        v4u k1 = *(const v4u*)(bc + r * 768 + 256 + lane * 4);
        v4u k2 = *(const v4u*)(bc + r * 768 + 512 + lane * 4);
        a8[r * 2 + ci] = dotq(k2, wq2, dotq(k1, wq1, dotq(k0, wq0, 0.f)));
      }
    }
    float krd = tree_reduce<8>(a8, lane);   // (r=(lane&7)>>1, ci=lane&1)
    float Kv = tanhf(krd + kb2c) * 0.5f;
    float An = Ab * (1.f - Kv * Kv);
    float cn = An * (s_own * c_own) + Kv * I_own + M_own;
    if (lane < 8) { A_own = An; c_own = cn; }
    float cnn = __shfl(cn, (lane + 1) & 63, 64);
    if (lane < 8 && !(lane & 1))
      mstore(ccw, pkf16(cn, cnn));
    xbar(++gen);
  }
}

// ---------------------------------------------------------------------------
// Workspace layout (bytes):
//   [0, 32M)    xn (reused as hs)
//   [32M, 96M)  gx
//   [96M,128M)  xmid
//   [128M, ..)  cpk 32K | ipk 32K | kpk 96K | flags 4K
// ---------------------------------------------------------------------------
extern "C" void kernel_launch(void* const* d_in, const int* in_sizes, int n_in,
                              void* d_out, int out_size, void* d_ws, size_t ws_size,
                              hipStream_t stream) {
  const float* x      = (const float*)d_in[0];
  const float* norm_w = (const float*)d_in[1];
  const float* W_ih   = (const float*)d_in[2];
  const float* b_ih   = (const float*)d_in[3];
  const float* W_hh   = (const float*)d_in[4];
  const float* b_hh   = (const float*)d_in[5];
  const float* loglam = (const float*)d_in[6];
  const float* kW1    = (const float*)d_in[7];
  const float* kb1    = (const float*)d_in[8];
  const float* kW2    = (const float*)d_in[9];
  const float* kb2    = (const float*)d_in[10];
  const float* Wo     = (const float*)d_in[11];
  float* out = (float*)d_out;

  char* ws = (char*)d_ws;
  float* xn   = (float*)(ws);
  float* gxb  = (float*)(ws + (size_t)33554432);
  float* xmid = (float*)(ws + (size_t)100663296);
  u32* cpk   = (u32*)(ws + (size_t)134217728);
  u32* ipk   = cpk + 8192;
  u32* kpk   = ipk + 8192;
  u32* flags = kpk + 24576;
  float* hs = xn;

  // memset zeroes initial c state AND all barrier generations each layer
  const size_t clr_bytes = (size_t)(8192 + 8192 + 24576 + 1024) * sizeof(u32);

  for (int l = 0; l < 2; ++l) {
    const float* xin = l ? (const float*)xmid : x;
    float* cout = l ? out : xmid;

    rmsnorm_kernel<<<BB * LSEQ, 256, 0, stream>>>(xin, norm_w, xn);

    gemm_fp32<<<dim3(256, 16), 256, 0, stream>>>(
        xn, W_ih + (size_t)l * DD * G2H, b_ih + (size_t)l * G2H, gxb,
        BB * LSEQ, G2H, DD);

    hipMemsetAsync(cpk, 0, clr_bytes, stream);

    scan_kernel<<<NG * GWG, 256, 0, stream>>>(
        gxb,
        W_hh + (size_t)l * HH * G2H, b_hh + (size_t)l * G2H,
        loglam + (size_t)l * HH,
        kW1 + (size_t)l * HH * K3H, kb1 + (size_t)l * K3H,
        kW2 + (size_t)l * K3H * HH, kb2 + (size_t)l * HH,
        cpk, ipk, kpk, flags, hs);

    gemm_fp32<<<dim3(256, 8), 256, 0, stream>>>(
        hs, Wo + (size_t)l * HH * DD, nullptr, cout,
        BB * LSEQ, DD, HH);
  }
}

// Round 6
// 12389.940 us; speedup vs baseline: 2.3477x; 1.5748x over previous
//
#include <hip/hip_runtime.h>
#include <math.h>

// Problem constants (match reference)
#define BB   32
#define LSEQ 512
#define DD   512
#define HH   512
#define G2H  1024
#define K3H  1536

// Scan: 8 groups x 64 WGs. Group g owns batch rows 4g..4g+3. WG slot s owns
// c/innov/K cols jz=8s..8s+7 and kmid cols jm=24s..24s+23. 256 thr = 4 waves.
//
// R6 = EXACT R0 protocol (master-aggregated padded-flag barrier, direct
// redundant data reads — the only pattern that ever hit 10us/step), with the
// communication SCOPE chosen at runtime:
//  FAST: groups formed from the hardware XCC_ID register (no placement
//        assumption): all 64 WGs of group g are physically on XCD g, so all
//        comm uses sc0 ops whose coherence point is the XCD-local L2
//        (~0.1-0.2us hops vs ~0.8us fabric hops). Engaged only if
//        (a) every XCD registered exactly 64 WGs, and (b) a bounded 2-WG
//        sc0 ping-pong probe (with a deterministic stale-L1 re-read leg)
//        passed on ALL XCDs. Decision made globally uniform via a
//        device-atomic rendezvous of all 512 co-resident WGs.
//  SLOW: exact R0 (sc1 through the memory-side cache). Proven 10.25ms.
// Cross-layer/replay staleness: end-of-dispatch L2 writeback + per-layer
// memset re-zeroes all comm/flag/ctl regions (order: flush < memset < next
// scan in-stream), so every mode combination reads zeros. All polls bounded:
// failure = fast garbage-fail, never a hang.
#define NG   8
#define GWG  64
#define FPAD 16

typedef unsigned int u32;
typedef _Float16 half2_t __attribute__((ext_vector_type(2)));
typedef u32 v4u __attribute__((ext_vector_type(4)));

template<bool B> struct BC { static constexpr bool v = B; };

// ---- scope-templated comm ops --------------------------------------------
// SYS=true : sc1 (fabric / memory-side coherence point)  [R0-proven]
// SYS=false: sc0 (L1-bypass, XCD-L2 coherence point)
template<bool SYS>
__device__ __forceinline__ void tload4(v4u& d, const u32* p) {
  if constexpr (SYS)
    asm volatile("global_load_dwordx4 %0, %1, off sc1" : "=v"(d) : "v"(p));
  else
    asm volatile("global_load_dwordx4 %0, %1, off sc0" : "=v"(d) : "v"(p));
}
template<bool SYS>
__device__ __forceinline__ void tstore(u32* p, u32 v) {
  if constexpr (SYS)
    asm volatile("global_store_dword %0, %1, off sc0 sc1" :: "v"(p), "v"(v)
                 : "memory");
  else
    asm volatile("global_store_dword %0, %1, off sc0" :: "v"(p), "v"(v)
                 : "memory");
}
__device__ __forceinline__ void vmwait0() {
  asm volatile("s_waitcnt vmcnt(0)" ::: "memory");
  __builtin_amdgcn_sched_barrier(0);
}
// fused load+wait poll (ordering correct by construction; rule #18 fence)
template<bool SYS>
__device__ __forceinline__ u32 tpoll(const u32* p) {
  u32 v;
  if constexpr (SYS)
    asm volatile("global_load_dword %0, %1, off sc1\n\ts_waitcnt vmcnt(0)"
                 : "=v"(v) : "v"(p) : "memory");
  else
    asm volatile("global_load_dword %0, %1, off sc0\n\ts_waitcnt vmcnt(0)"
                 : "=v"(v) : "v"(p) : "memory");
  __builtin_amdgcn_sched_barrier(0);
  return v;
}

__device__ __forceinline__ float dot2acc(u32 a, u32 b, float acc) {
#if __has_builtin(__builtin_amdgcn_fdot2)
  return __builtin_amdgcn_fdot2(__builtin_bit_cast(half2_t, a),
                                __builtin_bit_cast(half2_t, b), acc, false);
#else
  half2_t ha = __builtin_bit_cast(half2_t, a);
  half2_t hb = __builtin_bit_cast(half2_t, b);
  return acc + (float)ha[0] * (float)hb[0] + (float)ha[1] * (float)hb[1];
#endif
}
__device__ __forceinline__ float dotq(v4u a, v4u b, float acc) {
  acc = dot2acc(a.x, b.x, acc);
  acc = dot2acc(a.y, b.y, acc);
  acc = dot2acc(a.z, b.z, acc);
  acc = dot2acc(a.w, b.w, acc);
  return acc;
}
__device__ __forceinline__ u32 pkf16(float a, float b) {
#if __has_builtin(__builtin_amdgcn_cvt_pkrtz)
  return __builtin_bit_cast(u32, __builtin_amdgcn_cvt_pkrtz(a, b));
#else
  half2_t h; h[0] = (_Float16)a; h[1] = (_Float16)b;
  return __builtin_bit_cast(u32, h);
#endif
}

// In-register shuffle reduction trees (value for index lane&(M-1)).
template<int M> struct TreeC {
  static __device__ __forceinline__ void run(float* a, int lane, int d) {
    const bool hi = (lane & d) != 0;
#pragma unroll
    for (int i = 0; i < M / 2; ++i) {
      float mine  = hi ? a[2 * i + 1] : a[2 * i];
      float yours = hi ? a[2 * i]     : a[2 * i + 1];
      a[i] = mine + __shfl_xor(yours, d, 64);
    }
    TreeC<M / 2>::run(a, lane, d << 1);
  }
};
template<> struct TreeC<1> {
  static __device__ __forceinline__ void run(float*, int, int) {}
};
template<int M>
__device__ __forceinline__ float tree_reduce(float* a, int lane) {
  TreeC<M>::run(a, lane, 1);
  float v = a[0];
#pragma unroll
  for (int d = M; d <= 32; d <<= 1) v += __shfl_xor(v, d, 64);
  return v;
}

// ---------------------------------------------------------------------------
// RMSNorm: one 256-thread WG per row of 512.
// ---------------------------------------------------------------------------
__global__ __launch_bounds__(256)
void rmsnorm_kernel(const float* __restrict__ x, const float* __restrict__ w,
                    float* __restrict__ y)
{
  __shared__ float redl[256];
  const long row = blockIdx.x;
  const int t = threadIdx.x;
  const float* xr = x + row * DD;
  float v0 = xr[t], v1 = xr[t + 256];
  redl[t] = v0 * v0 + v1 * v1;
  __syncthreads();
  for (int off = 128; off > 0; off >>= 1) {
    if (t < off) redl[t] += redl[t + off];
    __syncthreads();
  }
  float scale = rsqrtf(redl[0] * (1.0f / 512.0f) + 1e-5f);
  float* yr = y + row * DD;
  yr[t]       = v0 * scale * w[t];
  yr[t + 256] = v1 * scale * w[t + 256];
}

// ---------------------------------------------------------------------------
// fp32 tiled GEMM: C[M,N] = A[M,K] @ B[K,N] (+ bias[n]), all row-major.
// ---------------------------------------------------------------------------
__global__ __launch_bounds__(256)
void gemm_fp32(const float* __restrict__ A, const float* __restrict__ B,
               const float* __restrict__ bias, float* __restrict__ C,
               int M, int N, int K)
{
  __shared__ float As[16][68];
  __shared__ float Bs[16][64];
  const int t  = threadIdx.x;
  const int tx = t & 15, ty = t >> 4;
  const long m0 = (long)blockIdx.x * 64;
  const long n0 = (long)blockIdx.y * 64;
  const int ar = t >> 2, ac = (t & 3) * 4;
  const int bk = t >> 4, bn = (t & 15) * 4;
  float acc[4][4] = {{0.f}};

  for (int k0 = 0; k0 < K; k0 += 16) {
    float4 av = *(const float4*)(A + (m0 + ar) * K + k0 + ac);
    float4 bv = *(const float4*)(B + (long)(k0 + bk) * N + n0 + bn);
    As[ac + 0][ar] = av.x; As[ac + 1][ar] = av.y;
    As[ac + 2][ar] = av.z; As[ac + 3][ar] = av.w;
    *(float4*)&Bs[bk][bn] = bv;
    __syncthreads();
#pragma unroll
    for (int kk = 0; kk < 16; ++kk) {
      float4 a = *(const float4*)&As[kk][ty * 4];
      float4 b = *(const float4*)&Bs[kk][tx * 4];
      acc[0][0] = fmaf(a.x, b.x, acc[0][0]); acc[0][1] = fmaf(a.x, b.y, acc[0][1]);
      acc[0][2] = fmaf(a.x, b.z, acc[0][2]); acc[0][3] = fmaf(a.x, b.w, acc[0][3]);
      acc[1][0] = fmaf(a.y, b.x, acc[1][0]); acc[1][1] = fmaf(a.y, b.y, acc[1][1]);
      acc[1][2] = fmaf(a.y, b.z, acc[1][2]); acc[1][3] = fmaf(a.y, b.w, acc[1][3]);
      acc[2][0] = fmaf(a.z, b.x, acc[2][0]); acc[2][1] = fmaf(a.z, b.y, acc[2][1]);
      acc[2][2] = fmaf(a.z, b.z, acc[2][2]); acc[2][3] = fmaf(a.z, b.w, acc[2][3]);
      acc[3][0] = fmaf(a.w, b.x, acc[3][0]); acc[3][1] = fmaf(a.w, b.y, acc[3][1]);
      acc[3][2] = fmaf(a.w, b.z, acc[3][2]); acc[3][3] = fmaf(a.w, b.w, acc[3][3]);
    }
    __syncthreads();
  }
  float4 bb = make_float4(0.f, 0.f, 0.f, 0.f);
  if (bias) bb = *(const float4*)(bias + n0 + tx * 4);
#pragma unroll
  for (int i = 0; i < 4; ++i) {
    float4 o;
    o.x = acc[i][0] + bb.x; o.y = acc[i][1] + bb.y;
    o.z = acc[i][2] + bb.z; o.w = acc[i][3] + bb.w;
    *(float4*)(C + (m0 + ty * 4 + i) * N + n0 + tx * 4) = o;
  }
}

// ---------------------------------------------------------------------------
// Persistent scan: 512 WGs x 256 thr, 64 KB static LDS (f16 weight pairs).
// Packed f16-pair comm arrays (R0 layout):
//   cpk[32][256] c | ipk[32][256] innov | kpk[32][768] kmid
// ctl: [0..7]=per-XCD WG counts, [8]=rendezvous, [16+x]=per-XCD probe-ok.
// pv:  per-XCD probe words (pA at x*2*FPAD, pB at +FPAD).
// ---------------------------------------------------------------------------
__global__ __launch_bounds__(256, 2)
void scan_kernel(const float* __restrict__ gx,
                 const float* __restrict__ Whh, const float* __restrict__ bhh,
                 const float* __restrict__ loglam,
                 const float* __restrict__ kW1, const float* __restrict__ kb1,
                 const float* __restrict__ kW2, const float* __restrict__ kb2,
                 u32* __restrict__ cpk, u32* __restrict__ ipk,
                 u32* __restrict__ kpk, u32* __restrict__ flags,
                 u32* __restrict__ ctl, u32* __restrict__ pv,
                 float* __restrict__ hs)
{
  const int blk  = blockIdx.x;
  const int tid  = threadIdx.x;
  const int q    = tid >> 6;        // wave 0..3
  const int lane = tid & 63;

  __shared__ u32 wh[16 * 256];      // 16 KB
  __shared__ u32 w1s[24 * 256];     // 24 KB
  __shared__ u32 w2s[8 * 768];      // 24 KB (total 64 KB)
  __shared__ u32 sh_slot, sh_mode;

  // ---- physical XCD id (no placement assumption) ----
  u32 xcd;
  asm volatile("s_getreg_b32 %0, hwreg(HW_REG_XCC_ID)" : "=s"(xcd));
  xcd &= 7u;

  // ---- register into this XCD's group ----
  if (tid == 0) {
    sh_slot = __hip_atomic_fetch_add(&ctl[xcd], 1u, __ATOMIC_RELAXED,
                                     __HIP_MEMORY_SCOPE_AGENT);
  }
  __syncthreads();
  const u32 dslot = sh_slot;

  // ---- bounded sc0 visibility probe (placement now guaranteed by XCC_ID;
  //      this tests ONLY sc0 store->load coherence at the XCD L2, incl. a
  //      deterministic stale-line re-read leg on slots 0 and 1) ----
  if (tid == 0 && dslot < GWG) {
    u32* pA = pv + (size_t)xcd * 2 * FPAD;
    u32* pB = pA + FPAD;
    int ok = 0, bud = 1 << 12;
    if (dslot == 0) {
      tstore<false>(pA, 1u);
      while (bud-- > 0) if (tpoll<false>(pB) == 1u) { ok = 1; break; }
      tstore<false>(pA, 2u);                 // round-2 ping for everyone else
    } else if (dslot == 1) {
      int a1 = 0, a2 = 0;
      while (bud-- > 0) if (tpoll<false>(pA) >= 1u) { a1 = 1; break; }
      tstore<false>(pB, 1u);
      // re-reads a line this WG already read -> stale-L1 detection
      while (bud-- > 0) if (tpoll<false>(pA) >= 2u) { a2 = 1; break; }
      ok = a1 & a2;
    } else {
      while (bud-- > 0) if (tpoll<false>(pA) >= 2u) { ok = 1; break; }
    }
    if (ok)
      __hip_atomic_fetch_add(&ctl[16 + xcd], 1u, __ATOMIC_RELAXED,
                             __HIP_MEMORY_SCOPE_AGENT);
  }

  // ---- grid rendezvous + globally-uniform mode decision ----
  if (tid == 0) {
    __hip_atomic_fetch_add(&ctl[8], 1u, __ATOMIC_RELEASE,
                           __HIP_MEMORY_SCOPE_AGENT);
    int bud = 1 << 24;
    while (bud-- > 0) {
      if (__hip_atomic_load(&ctl[8], __ATOMIC_ACQUIRE,
                            __HIP_MEMORY_SCOPE_AGENT) >= (u32)(NG * GWG))
        break;
    }
    u32 ok = 1;
    for (int x = 0; x < 8; ++x) {
      if (__hip_atomic_load(&ctl[x], __ATOMIC_RELAXED,
                            __HIP_MEMORY_SCOPE_AGENT) != (u32)GWG) ok = 0;
      if (__hip_atomic_load(&ctl[16 + x], __ATOMIC_RELAXED,
                            __HIP_MEMORY_SCOPE_AGENT) != (u32)GWG) ok = 0;
    }
    sh_mode = ok;
  }
  __syncthreads();
  const bool fast = (sh_mode != 0);

  const int g = fast ? (int)xcd   : (blk & 7);
  const int s = fast ? (int)dslot : (blk >> 3);
  const int jz = s * 8;
  const int jm = s * 24;

  // ---- one-time weight staging (fp32 -> f16 pairs; pair p <-> k=2p,2p+1) ----
  for (int idx = tid; idx < 16 * 256; idx += 256) {
    int c = idx >> 8, p = idx & 255;
    int gcol = (c < 8) ? (jz + c) : (512 + jz + (c - 8));
    wh[idx] = pkf16(Whh[(size_t)(2 * p) * G2H + gcol],
                    Whh[(size_t)(2 * p + 1) * G2H + gcol]);
  }
  for (int idx = tid; idx < 24 * 256; idx += 256) {
    int c = idx >> 8, p = idx & 255;
    w1s[idx] = pkf16(kW1[(size_t)(2 * p) * K3H + jm + c],
                     kW1[(size_t)(2 * p + 1) * K3H + jm + c]);
  }
  for (int idx = tid; idx < 8 * 768; idx += 256) {
    int c = idx / 768, p = idx - c * 768;
    w2s[idx] = pkf16(kW2[(size_t)(2 * p) * HH + jz + c],
                     kW2[(size_t)(2 * p + 1) * HH + jz + c]);
  }
  __syncthreads();   // weights visible

  // per-lane constants (state mapping: r=(lane>>1)&3, ci=lane&1, lanes<8)
  const int colA = jz + 2 * q + (lane & 1);
  const float Ab   = 1.f - expf(loglam[colA]);
  const float bz   = bhh[colA];
  const float bm   = bhh[512 + colA];
  const float kb2c = kb2[colA];
  int kb1i = lane & 7; if (kb1i > 5) kb1i = 5;
  const float kb1v = kb1[jm + 6 * q + kb1i];

  const int r_st  = (lane >> 1) & 3;
  const int growst = 4 * g + r_st;
  const size_t hsoff = (size_t)growst * LSEQ * HH + colA;
  const size_t gxoff = (size_t)growst * LSEQ * G2H + colA;

  const u32* crow[4]; const u32* irow[4]; const u32* krow[4];
#pragma unroll
  for (int r = 0; r < 4; ++r) {
    crow[r] = cpk + (size_t)(4 * g + r) * 256 + lane * 4;
    irow[r] = ipk + (size_t)(4 * g + r) * 256 + lane * 4;
    krow[r] = kpk + (size_t)(4 * g + r) * 768 + lane * 4;
  }
  u32* ciw = ipk + (size_t)growst * 256 + 4 * s + q;     // lanes<8 even
  u32* ccw = cpk + (size_t)growst * 256 + 4 * s + q;     // lanes<8 even
  const int rr2 = (lane >> 3) & 3, cc = lane & 7;        // S2 store map
  u32* ckw = kpk + (size_t)(4 * g + rr2) * 768 + 12 * s + 3 * q + (cc >> 1);

  u32* arrive = flags + (size_t)g * (GWG + 1) * FPAD;
  u32* goflag = arrive + (size_t)GWG * FPAD;

  int spin = 1 << 22;               // hang guard (shared across all polls)

  // ---- main loop, scope-templated; structure is EXACT R0 ----
  auto run = [&](auto sysc) {
    constexpr bool SYS = decltype(sysc)::v;
    float A_own = 0.f, c_own = 0.f, M_own = 0.f, I_own = 0.f, s_own = 1.f;
    u32 gen = 0;

    // R0 master-aggregated barrier (padded flags), scope-templated
    auto xbar = [&](u32 gv) {
      vmwait0();                    // comm stores at the coherence point
      __syncthreads();
      if (s == 0) {
        if (tid >= 1 && tid < GWG) {
          while (tpoll<SYS>(arrive + tid * FPAD) < gv)
            if (--spin < 0) break;
        }
        __syncthreads();
        if (tid == 0) tstore<SYS>(goflag, gv);
      } else {
        if (tid == 0) {
          tstore<SYS>(arrive + s * FPAD, gv);
          while (tpoll<SYS>(goflag) < gv)
            if (--spin < 0) break;
        }
      }
      __syncthreads();
    };

    for (int it = 0; it <= LSEQ; ++it) {
      // gx prefetch (cached, read-once)
      float gxz = 0.f, gxm = 0.f;
      if (lane < 8 && it < LSEQ) {
        gxz = gx[gxoff + (size_t)it * G2H];
        gxm = gx[gxoff + (size_t)it * G2H + 512];
      }

      // ---- S1: sumsq(c) -> s ; g = h@W_hh ; innov ----
      v4u cv0, cv1, cv2, cv3;
      tload4<SYS>(cv0, crow[0]); tload4<SYS>(cv1, crow[1]);
      tload4<SYS>(cv2, crow[2]); tload4<SYS>(cv3, crow[3]);
      vmwait0();
      float a4[4] = { dotq(cv0, cv0, 0.f), dotq(cv1, cv1, 0.f),
                      dotq(cv2, cv2, 0.f), dotq(cv3, cv3, 0.f) };
      float a16[16];
#pragma unroll
      for (int t = 0; t < 4; ++t) {        // t<2: z col 2q+t ; t>=2: m col
        int col = (t < 2) ? (2 * q + t) : (8 + 2 * q + (t - 2));
        v4u wq = *(const v4u*)(wh + col * 256 + lane * 4);
        a16[0 * 4 + t] = dotq(cv0, wq, 0.f);
        a16[1 * 4 + t] = dotq(cv1, wq, 0.f);
        a16[2 * 4 + t] = dotq(cv2, wq, 0.f);
        a16[3 * 4 + t] = dotq(cv3, wq, 0.f);
      }
      float ssv = tree_reduce<4>(a4, lane);     // row = lane&3
      float g16 = tree_reduce<16>(a16, lane);   // (r=(lane&15)>>2, t=lane&3)
      float sq  = __shfl(ssv, r_st, 64);
      float s_loc = fminf(1.f, 10.f * rsqrtf(sq + 1e-6f));
      float gz = __shfl(g16, (r_st * 4 + (lane & 1)) & 63, 64);
      float gm = __shfl(g16, (r_st * 4 + 2 + (lane & 1)) & 63, 64);
      if (lane < 8 && it >= 1)
        hs[hsoff + (size_t)(it - 1) * HH] = s_loc * c_own;
      if (it == LSEQ) break;
      float gzv = gz * s_loc + gxz + bz;
      float gmv = gm * s_loc + gxm + bm;
      float Mv = tanhf(gmv);
      float iv = gzv - A_own * (s_loc * c_own) - Mv;
      if (lane < 8) { M_own = Mv; I_own = iv; s_own = s_loc; }
      float ivn = __shfl(iv, (lane + 1) & 63, 64);
      if (lane < 8 && !(lane & 1))
        tstore<SYS>(ciw, pkf16(iv, ivn));
      xbar(++gen);

      // ---- S2: kmid = gelu(innov @ kW1 + kb1) ----
      v4u iv0, iv1, iv2, iv3;
      tload4<SYS>(iv0, irow[0]); tload4<SYS>(iv1, irow[1]);
      tload4<SYS>(iv2, irow[2]); tload4<SYS>(iv3, irow[3]);
      vmwait0();
      float a32[32];
#pragma unroll
      for (int i = 0; i < 32; ++i) a32[i] = 0.f;
#pragma unroll
      for (int cj = 0; cj < 6; ++cj) {
        v4u wq = *(const v4u*)(w1s + (6 * q + cj) * 256 + lane * 4);
        a32[0 * 8 + cj] = dotq(iv0, wq, 0.f);
        a32[1 * 8 + cj] = dotq(iv1, wq, 0.f);
        a32[2 * 8 + cj] = dotq(iv2, wq, 0.f);
        a32[3 * 8 + cj] = dotq(iv3, wq, 0.f);
      }
      float t32 = tree_reduce<32>(a32, lane);   // (r=(lane&31)>>3, cc=lane&7)
      float kvb = t32 + kb1v;
      float gl = 0.5f * kvb * (1.f + erff(kvb * 0.7071067811865476f));
      float gln = __shfl(gl, (lane + 1) & 63, 64);
      if (lane < 32 && !(lane & 1) && cc < 6)
        tstore<SYS>(ckw, pkf16(gl, gln));
      xbar(++gen);

      // ---- S3: K = tanh(kmid @ kW2 + kb2)*0.5 ; c update ----
      v4u k00,k01,k02, k10,k11,k12, k20,k21,k22, k30,k31,k32;
      tload4<SYS>(k00, krow[0]); tload4<SYS>(k01, krow[0]+256); tload4<SYS>(k02, krow[0]+512);
      tload4<SYS>(k10, krow[1]); tload4<SYS>(k11, krow[1]+256); tload4<SYS>(k12, krow[1]+512);
      tload4<SYS>(k20, krow[2]); tload4<SYS>(k21, krow[2]+256); tload4<SYS>(k22, krow[2]+512);
      tload4<SYS>(k30, krow[3]); tload4<SYS>(k31, krow[3]+256); tload4<SYS>(k32, krow[3]+512);
      vmwait0();
      float a8[8];
#pragma unroll
      for (int ci = 0; ci < 2; ++ci) {
        const u32* wc = w2s + (2 * q + ci) * 768 + lane * 4;
        v4u wq0 = *(const v4u*)(wc);
        v4u wq1 = *(const v4u*)(wc + 256);
        v4u wq2 = *(const v4u*)(wc + 512);
        a8[0 * 2 + ci] = dotq(k02, wq2, dotq(k01, wq1, dotq(k00, wq0, 0.f)));
        a8[1 * 2 + ci] = dotq(k12, wq2, dotq(k11, wq1, dotq(k10, wq0, 0.f)));
        a8[2 * 2 + ci] = dotq(k22, wq2, dotq(k21, wq1, dotq(k20, wq0, 0.f)));
        a8[3 * 2 + ci] = dotq(k32, wq2, dotq(k31, wq1, dotq(k30, wq0, 0.f)));
      }
      float krd = tree_reduce<8>(a8, lane);   // (r=(lane&7)>>1, ci=lane&1)
      float Kv = tanhf(krd + kb2c) * 0.5f;
      float An = Ab * (1.f - Kv * Kv);
      float cn = An * (s_own * c_own) + Kv * I_own + M_own;
      if (lane < 8) { A_own = An; c_own = cn; }
      float cnn = __shfl(cn, (lane + 1) & 63, 64);
      if (lane < 8 && !(lane & 1))
        tstore<SYS>(ccw, pkf16(cn, cnn));
      xbar(++gen);
    }
  };
  if (fast) run(BC<false>{});
  else      run(BC<true>{});
}

// ---------------------------------------------------------------------------
// Workspace layout (bytes):
//   [0, 32M)    xn (reused as hs)
//   [32M, 96M)  gx
//   [96M,128M)  xmid
//   [128M, ..)  cpk 32K | ipk 32K | kpk 96K | flags 33K | ctl 256B | pv 1K
// ---------------------------------------------------------------------------
extern "C" void kernel_launch(void* const* d_in, const int* in_sizes, int n_in,
                              void* d_out, int out_size, void* d_ws, size_t ws_size,
                              hipStream_t stream) {
  const float* x      = (const float*)d_in[0];
  const float* norm_w = (const float*)d_in[1];
  const float* W_ih   = (const float*)d_in[2];
  const float* b_ih   = (const float*)d_in[3];
  const float* W_hh   = (const float*)d_in[4];
  const float* b_hh   = (const float*)d_in[5];
  const float* loglam = (const float*)d_in[6];
  const float* kW1    = (const float*)d_in[7];
  const float* kb1    = (const float*)d_in[8];
  const float* kW2    = (const float*)d_in[9];
  const float* kb2    = (const float*)d_in[10];
  const float* Wo     = (const float*)d_in[11];
  float* out = (float*)d_out;

  char* ws = (char*)d_ws;
  float* xn   = (float*)(ws);
  float* gxb  = (float*)(ws + (size_t)33554432);
  float* xmid = (float*)(ws + (size_t)100663296);
  u32* cpk   = (u32*)(ws + (size_t)134217728);
  u32* ipk   = cpk + 8192;
  u32* kpk   = ipk + 8192;
  u32* flags = kpk + 24576;                 // NG*(GWG+1)*FPAD = 8320 words
  u32* ctl   = flags + 8320;                // 64 words
  u32* pv    = ctl + 64;                    // 8*2*FPAD = 256 words
  float* hs = xn;

  const size_t clr_bytes =
      (size_t)(8192 + 8192 + 24576 + 8320 + 64 + 256) * sizeof(u32);

  for (int l = 0; l < 2; ++l) {
    const float* xin = l ? (const float*)xmid : x;
    float* cout = l ? out : xmid;

    rmsnorm_kernel<<<BB * LSEQ, 256, 0, stream>>>(xin, norm_w, xn);

    gemm_fp32<<<dim3(256, 16), 256, 0, stream>>>(
        xn, W_ih + (size_t)l * DD * G2H, b_ih + (size_t)l * G2H, gxb,
        BB * LSEQ, G2H, DD);

    // zero initial c, barrier flags, registration/probe control each layer
    hipMemsetAsync(cpk, 0, clr_bytes, stream);

    scan_kernel<<<NG * GWG, 256, 0, stream>>>(
        gxb,
        W_hh + (size_t)l * HH * G2H, b_hh + (size_t)l * G2H,
        loglam + (size_t)l * HH,
        kW1 + (size_t)l * HH * K3H, kb1 + (size_t)l * K3H,
        kW2 + (size_t)l * K3H * HH, kb2 + (size_t)l * HH,
        cpk, ipk, kpk, flags, ctl, pv, hs);

    gemm_fp32<<<dim3(256, 8), 256, 0, stream>>>(
        hs, Wo + (size_t)l * HH * DD, nullptr, cout,
        BB * LSEQ, DD, HH);
  }
}

// Round 7
// 12297.137 us; speedup vs baseline: 2.3654x; 1.0075x over previous
//
#include <hip/hip_runtime.h>
#include <math.h>

// Problem constants (match reference)
#define BB   32
#define LSEQ 512
#define DD   512
#define HH   512
#define G2H  1024
#define K3H  1536

// Scan: 8 groups x 64 WGs (group = blk&7). Group g owns batch rows 4g..4g+3.
// WG slot s owns c/innov/K cols jz=8s..8s+7 and kmid cols jm=24s..24s+23.
// WG = 256 thr = 4 waves; wave q owns col pair (2 c-cols / 6 kmid-cols) x 4 rows.
//
// R7 = EXACT R0 protocol (master-aggregated padded-flag barrier via sc1 ops +
// relaxed agent-scope atomic polls — the only pattern that ever hit 10us/step)
// with ONE change under test: COOPERATIVE PAYLOAD GATHER. The WG's 256
// threads load each phase's 4-row payload ONCE (contiguous region), bounce it
// through a 12KB LDS buffer, and all 4 waves compute from LDS. Cuts the
// coherent gather 40 MB/step -> 10 MB/step (R0: every wave redundantly
// re-loads everything = 4x amplification; measured 3.9 TB/s at the MALL).
// R5 tested this bundled with a congesting distributed barrier (unattributable
// regression); this round isolates the read-pattern change against the proven
// barrier. All other code verbatim R0.
//
// CO-RESIDENCY: LDS 76KB + launch_bounds(256,2) => 2 WG/CU => all 512 WGs
// resident (proven at this footprint in R3/R5).
// HANG GUARD: bounded polls; exhaustion exits the poll only (phase structure
// preserved) -> fast garbage fail, never a hang.
#define NG   8
#define GWG  64
#define FPAD 16

typedef unsigned int u32;
typedef _Float16 half2_t __attribute__((ext_vector_type(2)));
typedef u32 v4u __attribute__((ext_vector_type(4)));

// ---- coherence-point memory ops (R0-proven) -------------------------------
__device__ __forceinline__ void mload4(v4u& d, const u32* p) {
  asm volatile("global_load_dwordx4 %0, %1, off sc1" : "=v"(d) : "v"(p));
}
// Wait all outstanding vmem. The "memory" clobber keeps subsequent memory ops
// (incl. the LDS bounce write) from moving above the wait; sched_barrier
// additionally fences register-only consumers (rule #18).
__device__ __forceinline__ void vmwait0() {
  asm volatile("s_waitcnt vmcnt(0)" ::: "memory");
  __builtin_amdgcn_sched_barrier(0);
}
__device__ __forceinline__ void mstore(u32* p, u32 v) {
  asm volatile("global_store_dword %0, %1, off sc0 sc1" :: "v"(p), "v"(v)
               : "memory");
}

__device__ __forceinline__ float dot2acc(u32 a, u32 b, float acc) {
#if __has_builtin(__builtin_amdgcn_fdot2)
  return __builtin_amdgcn_fdot2(__builtin_bit_cast(half2_t, a),
                                __builtin_bit_cast(half2_t, b), acc, false);
#else
  half2_t ha = __builtin_bit_cast(half2_t, a);
  half2_t hb = __builtin_bit_cast(half2_t, b);
  return acc + (float)ha[0] * (float)hb[0] + (float)ha[1] * (float)hb[1];
#endif
}
__device__ __forceinline__ float dotq(v4u a, v4u b, float acc) {
  acc = dot2acc(a.x, b.x, acc);
  acc = dot2acc(a.y, b.y, acc);
  acc = dot2acc(a.z, b.z, acc);
  acc = dot2acc(a.w, b.w, acc);
  return acc;
}
__device__ __forceinline__ u32 pkf16(float a, float b) {
#if __has_builtin(__builtin_amdgcn_cvt_pkrtz)
  return __builtin_bit_cast(u32, __builtin_amdgcn_cvt_pkrtz(a, b));
#else
  half2_t h; h[0] = (_Float16)a; h[1] = (_Float16)b;
  return __builtin_bit_cast(u32, h);
#endif
}

// In-register shuffle reduction trees (value for index lane&(M-1)).
template<int M> struct TreeC {
  static __device__ __forceinline__ void run(float* a, int lane, int d) {
    const bool hi = (lane & d) != 0;
#pragma unroll
    for (int i = 0; i < M / 2; ++i) {
      float mine  = hi ? a[2 * i + 1] : a[2 * i];
      float yours = hi ? a[2 * i]     : a[2 * i + 1];
      a[i] = mine + __shfl_xor(yours, d, 64);
    }
    TreeC<M / 2>::run(a, lane, d << 1);
  }
};
template<> struct TreeC<1> {
  static __device__ __forceinline__ void run(float*, int, int) {}
};
template<int M>
__device__ __forceinline__ float tree_reduce(float* a, int lane) {
  TreeC<M>::run(a, lane, 1);
  float v = a[0];
#pragma unroll
  for (int d = M; d <= 32; d <<= 1) v += __shfl_xor(v, d, 64);
  return v;
}

// ---------------------------------------------------------------------------
// RMSNorm: one 256-thread WG per row of 512.
// ---------------------------------------------------------------------------
__global__ __launch_bounds__(256)
void rmsnorm_kernel(const float* __restrict__ x, const float* __restrict__ w,
                    float* __restrict__ y)
{
  __shared__ float redl[256];
  const long row = blockIdx.x;
  const int t = threadIdx.x;
  const float* xr = x + row * DD;
  float v0 = xr[t], v1 = xr[t + 256];
  redl[t] = v0 * v0 + v1 * v1;
  __syncthreads();
  for (int off = 128; off > 0; off >>= 1) {
    if (t < off) redl[t] += redl[t + off];
    __syncthreads();
  }
  float scale = rsqrtf(redl[0] * (1.0f / 512.0f) + 1e-5f);
  float* yr = y + row * DD;
  yr[t]       = v0 * scale * w[t];
  yr[t + 256] = v1 * scale * w[t + 256];
}

// ---------------------------------------------------------------------------
// fp32 tiled GEMM: C[M,N] = A[M,K] @ B[K,N] (+ bias[n]), all row-major.
// ---------------------------------------------------------------------------
__global__ __launch_bounds__(256)
void gemm_fp32(const float* __restrict__ A, const float* __restrict__ B,
               const float* __restrict__ bias, float* __restrict__ C,
               int M, int N, int K)
{
  __shared__ float As[16][68];
  __shared__ float Bs[16][64];
  const int t  = threadIdx.x;
  const int tx = t & 15, ty = t >> 4;
  const long m0 = (long)blockIdx.x * 64;
  const long n0 = (long)blockIdx.y * 64;
  const int ar = t >> 2, ac = (t & 3) * 4;
  const int bk = t >> 4, bn = (t & 15) * 4;
  float acc[4][4] = {{0.f}};

  for (int k0 = 0; k0 < K; k0 += 16) {
    float4 av = *(const float4*)(A + (m0 + ar) * K + k0 + ac);
    float4 bv = *(const float4*)(B + (long)(k0 + bk) * N + n0 + bn);
    As[ac + 0][ar] = av.x; As[ac + 1][ar] = av.y;
    As[ac + 2][ar] = av.z; As[ac + 3][ar] = av.w;
    *(float4*)&Bs[bk][bn] = bv;
    __syncthreads();
#pragma unroll
    for (int kk = 0; kk < 16; ++kk) {
      float4 a = *(const float4*)&As[kk][ty * 4];
      float4 b = *(const float4*)&Bs[kk][tx * 4];
      acc[0][0] = fmaf(a.x, b.x, acc[0][0]); acc[0][1] = fmaf(a.x, b.y, acc[0][1]);
      acc[0][2] = fmaf(a.x, b.z, acc[0][2]); acc[0][3] = fmaf(a.x, b.w, acc[0][3]);
      acc[1][0] = fmaf(a.y, b.x, acc[1][0]); acc[1][1] = fmaf(a.y, b.y, acc[1][1]);
      acc[1][2] = fmaf(a.y, b.z, acc[1][2]); acc[1][3] = fmaf(a.y, b.w, acc[1][3]);
      acc[2][0] = fmaf(a.z, b.x, acc[2][0]); acc[2][1] = fmaf(a.z, b.y, acc[2][1]);
      acc[2][2] = fmaf(a.z, b.z, acc[2][2]); acc[2][3] = fmaf(a.z, b.w, acc[2][3]);
      acc[3][0] = fmaf(a.w, b.x, acc[3][0]); acc[3][1] = fmaf(a.w, b.y, acc[3][1]);
      acc[3][2] = fmaf(a.w, b.z, acc[3][2]); acc[3][3] = fmaf(a.w, b.w, acc[3][3]);
    }
    __syncthreads();
  }
  float4 bb = make_float4(0.f, 0.f, 0.f, 0.f);
  if (bias) bb = *(const float4*)(bias + n0 + tx * 4);
#pragma unroll
  for (int i = 0; i < 4; ++i) {
    float4 o;
    o.x = acc[i][0] + bb.x; o.y = acc[i][1] + bb.y;
    o.z = acc[i][2] + bb.z; o.w = acc[i][3] + bb.w;
    *(float4*)(C + (m0 + ty * 4 + i) * N + n0 + tx * 4) = o;
  }
}

// ---------------------------------------------------------------------------
// Persistent scan: 512 WGs x 256 thr, 76 KB static LDS.
// Packed f16-pair comm arrays (R0 layout, dword d <-> cols 2d,2d+1):
//   cpk[32][256] c | ipk[32][256] innov | kpk[32][768] kmid
// Flags: arrive[g][64] padded FPAD + go flag per group (R0 layout).
// ---------------------------------------------------------------------------
__global__ __launch_bounds__(256, 2)
void scan_kernel(const float* __restrict__ gx,
                 const float* __restrict__ Whh, const float* __restrict__ bhh,
                 const float* __restrict__ loglam,
                 const float* __restrict__ kW1, const float* __restrict__ kb1,
                 const float* __restrict__ kW2, const float* __restrict__ kb2,
                 u32* __restrict__ cpk, u32* __restrict__ ipk,
                 u32* __restrict__ kpk, u32* __restrict__ flags,
                 float* __restrict__ hs)
{
  const int blk  = blockIdx.x;
  const int g    = blk & 7;         // group (rows 4g..4g+3)
  const int s    = blk >> 3;        // slot 0..63
  const int tid  = threadIdx.x;
  const int q    = tid >> 6;        // wave 0..3
  const int lane = tid & 63;
  const int jz   = s * 8;
  const int jm   = s * 24;

  __shared__ u32 wh[16 * 256];      // 16 KB: 8 z-cols + 8 m-cols, f16 pairs
  __shared__ u32 w1s[24 * 256];     // 24 KB
  __shared__ u32 w2s[8 * 768];      // 24 KB
  __shared__ u32 bc[4 * 768];       // 12 KB payload bounce (total 76 KB)

  // ---- one-time weight staging (fp32 -> f16 pairs; pair p <-> k=2p,2p+1) ----
  for (int idx = tid; idx < 16 * 256; idx += 256) {
    int c = idx >> 8, p = idx & 255;
    int gcol = (c < 8) ? (jz + c) : (512 + jz + (c - 8));
    wh[idx] = pkf16(Whh[(size_t)(2 * p) * G2H + gcol],
                    Whh[(size_t)(2 * p + 1) * G2H + gcol]);
  }
  for (int idx = tid; idx < 24 * 256; idx += 256) {
    int c = idx >> 8, p = idx & 255;
    w1s[idx] = pkf16(kW1[(size_t)(2 * p) * K3H + jm + c],
                     kW1[(size_t)(2 * p + 1) * K3H + jm + c]);
  }
  for (int idx = tid; idx < 8 * 768; idx += 256) {
    int c = idx / 768, p = idx - c * 768;
    w2s[idx] = pkf16(kW2[(size_t)(2 * p) * HH + jz + c],
                     kW2[(size_t)(2 * p + 1) * HH + jz + c]);
  }
  __syncthreads();   // weights + bc usable

  // per-lane constants (state mapping: r=(lane>>1)&3, ci=lane&1, lanes<8)
  const int colA = jz + 2 * q + (lane & 1);
  const float Ab   = 1.f - expf(loglam[colA]);
  const float bz   = bhh[colA];
  const float bm   = bhh[512 + colA];
  const float kb2c = kb2[colA];
  int kb1i = lane & 7; if (kb1i > 5) kb1i = 5;
  const float kb1v = kb1[jm + 6 * q + kb1i];

  const int r_st  = (lane >> 1) & 3;
  const int growst = 4 * g + r_st;
  const size_t hsoff = (size_t)growst * LSEQ * HH + colA;
  const size_t gxoff = (size_t)growst * LSEQ * G2H + colA;

  // group-contiguous payload bases (rows 4g..4g+3)
  const u32* cg = cpk + (size_t)(4 * g) * 256;   // 1024 words
  const u32* ig = ipk + (size_t)(4 * g) * 256;   // 1024 words
  const u32* kg = kpk + (size_t)(4 * g) * 768;   // 3072 words

  // store pointers (R0 mapping)
  u32* ciw = ipk + (size_t)growst * 256 + 4 * s + q;               // lanes<8 even
  u32* ccw = cpk + (size_t)growst * 256 + 4 * s + q;               // lanes<8 even
  const int rr = (lane >> 3) & 3, cc = lane & 7;                   // S2 map
  u32* ckw = kpk + (size_t)(4 * g + rr) * 768 + 12 * s + 3 * q + (cc >> 1);

  u32* arrive = flags + (size_t)g * (GWG + 1) * FPAD;
  u32* goflag = arrive + (size_t)GWG * FPAD;

  float A_own = 0.f, c_own = 0.f, M_own = 0.f, I_own = 0.f, s_own = 1.f;
  int spin = 1 << 22;               // hang guard
  u32 gen = 0;

  // R0 master-aggregated barrier (padded flags) + hang guard
  auto xbar = [&](u32 gv) {
    vmwait0();                      // comm stores at coherence point
    __syncthreads();
    if (s == 0) {
      if (tid >= 1 && tid < GWG) {
        while (__hip_atomic_load(&arrive[tid * FPAD], __ATOMIC_RELAXED,
                                 __HIP_MEMORY_SCOPE_AGENT) < gv)
          if (--spin < 0) break;
      }
      __syncthreads();
      if (tid == 0) mstore(goflag, gv);
    } else {
      if (tid == 0) {
        mstore(arrive + s * FPAD, gv);
        while (__hip_atomic_load(goflag, __ATOMIC_RELAXED,
                                 __HIP_MEMORY_SCOPE_AGENT) < gv)
          if (--spin < 0) break;
      }
    }
    __syncthreads();
  };

  for (int it = 0; it <= LSEQ; ++it) {
    // gx prefetch (cached, read-once) — overlaps the S1 gather
    float gxz = 0.f, gxm = 0.f;
    if (lane < 8 && it < LSEQ) {
      gxz = gx[gxoff + (size_t)it * G2H];
      gxm = gx[gxoff + (size_t)it * G2H + 512];
    }

    // ---- S1: coop-gather c(it) [1024 words once], compute from LDS ----
    {
      v4u v;
      mload4(v, cg + tid * 4);
      vmwait0();
      *(v4u*)(bc + tid * 4) = v;
    }
    __syncthreads();
    v4u cv[4];
#pragma unroll
    for (int r = 0; r < 4; ++r) cv[r] = *(const v4u*)(bc + r * 256 + lane * 4);

    float a4[4] = { dotq(cv[0], cv[0], 0.f), dotq(cv[1], cv[1], 0.f),
                    dotq(cv[2], cv[2], 0.f), dotq(cv[3], cv[3], 0.f) };
    float a16[16];
#pragma unroll
    for (int t = 0; t < 4; ++t) {          // t<2: z col 2q+t ; t>=2: m col
      int col = (t < 2) ? (2 * q + t) : (8 + 2 * q + (t - 2));
      v4u wq = *(const v4u*)(wh + col * 256 + lane * 4);
      a16[0 * 4 + t] = dotq(cv[0], wq, 0.f);
      a16[1 * 4 + t] = dotq(cv[1], wq, 0.f);
      a16[2 * 4 + t] = dotq(cv[2], wq, 0.f);
      a16[3 * 4 + t] = dotq(cv[3], wq, 0.f);
    }
    float ssv = tree_reduce<4>(a4, lane);     // row = lane&3
    float g16 = tree_reduce<16>(a16, lane);   // (r=(lane&15)>>2, t=lane&3)
    float sq  = __shfl(ssv, r_st, 64);
    float s_loc = fminf(1.f, 10.f * rsqrtf(sq + 1e-6f));
    float gz = __shfl(g16, (r_st * 4 + (lane & 1)) & 63, 64);
    float gm = __shfl(g16, (r_st * 4 + 2 + (lane & 1)) & 63, 64);
    if (lane < 8 && it >= 1)
      hs[hsoff + (size_t)(it - 1) * HH] = s_loc * c_own;
    if (it == LSEQ) break;
    float gzv = gz * s_loc + gxz + bz;
    float gmv = gm * s_loc + gxm + bm;
    float Mv = tanhf(gmv);
    float iv = gzv - A_own * (s_loc * c_own) - Mv;
    if (lane < 8) { M_own = Mv; I_own = iv; s_own = s_loc; }
    float ivn = __shfl(iv, (lane + 1) & 63, 64);
    if (lane < 8 && !(lane & 1))
      mstore(ciw, pkf16(iv, ivn));
    xbar(++gen);

    // ---- S2: coop-gather innov [1024 words once], kmid = gelu(innov@kW1) ----
    {
      v4u v;
      mload4(v, ig + tid * 4);
      vmwait0();
      *(v4u*)(bc + tid * 4) = v;
    }
    __syncthreads();
    v4u pv[4];
#pragma unroll
    for (int r = 0; r < 4; ++r) pv[r] = *(const v4u*)(bc + r * 256 + lane * 4);

    float a32[32];
#pragma unroll
    for (int i = 0; i < 32; ++i) a32[i] = 0.f;
#pragma unroll
    for (int cj = 0; cj < 6; ++cj) {
      v4u wq = *(const v4u*)(w1s + (6 * q + cj) * 256 + lane * 4);
      a32[0 * 8 + cj] = dotq(pv[0], wq, 0.f);
      a32[1 * 8 + cj] = dotq(pv[1], wq, 0.f);
      a32[2 * 8 + cj] = dotq(pv[2], wq, 0.f);
      a32[3 * 8 + cj] = dotq(pv[3], wq, 0.f);
    }
    float t32 = tree_reduce<32>(a32, lane);   // (r=(lane&31)>>3, cc=lane&7)
    float kvb = t32 + kb1v;
    float gl = 0.5f * kvb * (1.f + erff(kvb * 0.7071067811865476f));
    float gln = __shfl(gl, (lane + 1) & 63, 64);
    if (lane < 32 && !(lane & 1) && cc < 6)
      mstore(ckw, pkf16(gl, gln));
    xbar(++gen);

    // ---- S3: coop-gather kmid [3072 words once], K = tanh(kmid@kW2)*0.5 ----
    {
      v4u v0, v1, v2;
      mload4(v0, kg + tid * 4);
      mload4(v1, kg + 1024 + tid * 4);
      mload4(v2, kg + 2048 + tid * 4);
      vmwait0();
      *(v4u*)(bc + tid * 4) = v0;
      *(v4u*)(bc + 1024 + tid * 4) = v1;
      *(v4u*)(bc + 2048 + tid * 4) = v2;
    }
    __syncthreads();
    float a8[8];
#pragma unroll
    for (int ci = 0; ci < 2; ++ci) {
      const u32* wc = w2s + (2 * q + ci) * 768 + lane * 4;
      v4u wq0 = *(const v4u*)(wc);
      v4u wq1 = *(const v4u*)(wc + 256);
      v4u wq2 = *(const v4u*)(wc + 512);
#pragma unroll
      for (int r = 0; r < 4; ++r) {
        v4u k0 = *(const v4u*)(bc + r * 768 +   0 + lane * 4);
        v4u k1 = *(const v4u*)(bc + r * 768 + 256 + lane * 4);
        v4u k2 = *(const v4u*)(bc + r * 768 + 512 + lane * 4);
        a8[r * 2 + ci] = dotq(k2, wq2, dotq(k1, wq1, dotq(k0, wq0, 0.f)));
      }
    }
    float krd = tree_reduce<8>(a8, lane);   // (r=(lane&7)>>1, ci=lane&1)
    float Kv = tanhf(krd + kb2c) * 0.5f;
    float An = Ab * (1.f - Kv * Kv);
    float cn = An * (s_own * c_own) + Kv * I_own + M_own;
    if (lane < 8) { A_own = An; c_own = cn; }
    float cnn = __shfl(cn, (lane + 1) & 63, 64);
    if (lane < 8 && !(lane & 1))
      mstore(ccw, pkf16(cn, cnn));
    xbar(++gen);
  }
}

// ---------------------------------------------------------------------------
// Workspace layout (bytes):
//   [0, 32M)    xn (reused as hs)
//   [32M, 96M)  gx
//   [96M,128M)  xmid
//   [128M, ..)  cpk 32K | ipk 32K | kpk 96K | flags 33K
// ---------------------------------------------------------------------------
extern "C" void kernel_launch(void* const* d_in, const int* in_sizes, int n_in,
                              void* d_out, int out_size, void* d_ws, size_t ws_size,
                              hipStream_t stream) {
  const float* x      = (const float*)d_in[0];
  const float* norm_w = (const float*)d_in[1];
  const float* W_ih   = (const float*)d_in[2];
  const float* b_ih   = (const float*)d_in[3];
  const float* W_hh   = (const float*)d_in[4];
  const float* b_hh   = (const float*)d_in[5];
  const float* loglam = (const float*)d_in[6];
  const float* kW1    = (const float*)d_in[7];
  const float* kb1    = (const float*)d_in[8];
  const float* kW2    = (const float*)d_in[9];
  const float* kb2    = (const float*)d_in[10];
  const float* Wo     = (const float*)d_in[11];
  float* out = (float*)d_out;

  char* ws = (char*)d_ws;
  float* xn   = (float*)(ws);
  float* gxb  = (float*)(ws + (size_t)33554432);
  float* xmid = (float*)(ws + (size_t)100663296);
  u32* cpk   = (u32*)(ws + (size_t)134217728);
  u32* ipk   = cpk + 8192;
  u32* kpk   = ipk + 8192;
  u32* flags = kpk + 24576;                 // NG*(GWG+1)*FPAD = 8320 words
  float* hs = xn;

  // memset zeroes initial c state, innov/kmid regions, and all barrier flags
  const size_t clr_bytes = (size_t)(8192 + 8192 + 24576 + 8320) * sizeof(u32);

  for (int l = 0; l < 2; ++l) {
    const float* xin = l ? (const float*)xmid : x;
    float* cout = l ? out : xmid;

    rmsnorm_kernel<<<BB * LSEQ, 256, 0, stream>>>(xin, norm_w, xn);

    gemm_fp32<<<dim3(256, 16), 256, 0, stream>>>(
        xn, W_ih + (size_t)l * DD * G2H, b_ih + (size_t)l * G2H, gxb,
        BB * LSEQ, G2H, DD);

    hipMemsetAsync(cpk, 0, clr_bytes, stream);

    scan_kernel<<<NG * GWG, 256, 0, stream>>>(
        gxb,
        W_hh + (size_t)l * HH * G2H, b_hh + (size_t)l * G2H,
        loglam + (size_t)l * HH,
        kW1 + (size_t)l * HH * K3H, kb1 + (size_t)l * K3H,
        kW2 + (size_t)l * K3H * HH, kb2 + (size_t)l * HH,
        cpk, ipk, kpk, flags, hs);

    gemm_fp32<<<dim3(256, 8), 256, 0, stream>>>(
        hs, Wo + (size_t)l * HH * DD, nullptr, cout,
        BB * LSEQ, DD, HH);
  }
}

// Round 8
// 10400.961 us; speedup vs baseline: 2.7967x; 1.1823x over previous
//
#include <hip/hip_runtime.h>
#include <math.h>

// Problem constants (match reference)
#define BB   32
#define LSEQ 512
#define DD   512
#define HH   512
#define G2H  1024
#define K3H  1536

// Scan: 8 groups x 64 WGs (group = blk&7 — NO placement assumption; all comm
// goes through the memory-side Infinity Cache via explicit sc-flagged ops).
// Group g owns batch rows 4g..4g+3. WG slot s owns c/innov/K cols jz=8s..8s+7
// and kmid cols jm=24s..24s+23. WG = 256 thr = 4 waves; wave q owns col
// quarter (2 c-cols, 6 kmid-cols) x all 4 rows. 64 KB static LDS of f16
// weights => exactly 2 WGs/CU => all 512 co-resident (pigeonhole).
//
// FINAL (R8 = exact R0 revert): this master-aggregated padded-flag barrier +
// redundant per-wave post-barrier data loads is the best-measured exchange
// mechanism on this fabric (10 us/step). Falsified alternatives: tagged
// continuous polling (R2/R3: congestion), sc0 XCD-local coherence (R4/R6:
// probe-rejected), distributed compact barrier (R5: congestion), cooperative
// LDS-bounced gather (R7: latency-neutral + bounce tax). The scan is
// latency-structural: 512 steps x 3 irreducible cross-WG exchanges.
#define NG   8
#define GWG  64
#define FPAD 16

typedef unsigned int u32;
typedef _Float16 half2_t __attribute__((ext_vector_type(2)));
typedef u32 v4u __attribute__((ext_vector_type(4)));

// ---- coherence-point memory ops (same mechanism as the proven flag polls) --
__device__ __forceinline__ void mload4(v4u& d, const u32* p) {
  asm volatile("global_load_dwordx4 %0, %1, off sc1" : "=v"(d) : "v"(p));
}
// waitcnt that TIES the loaded regs so uses can't be scheduled before it
__device__ __forceinline__ void vmwait4(v4u& a, v4u& b, v4u& c, v4u& d) {
  asm volatile("s_waitcnt vmcnt(0)"
               : "+v"(a), "+v"(b), "+v"(c), "+v"(d) :: "memory");
}
__device__ __forceinline__ void mstore(u32* p, u32 v) {
  asm volatile("global_store_dword %0, %1, off sc0 sc1" :: "v"(p), "v"(v)
               : "memory");
}

__device__ __forceinline__ float dot2acc(u32 a, u32 b, float acc) {
#if __has_builtin(__builtin_amdgcn_fdot2)
  return __builtin_amdgcn_fdot2(__builtin_bit_cast(half2_t, a),
                                __builtin_bit_cast(half2_t, b), acc, false);
#else
  half2_t ha = __builtin_bit_cast(half2_t, a);
  half2_t hb = __builtin_bit_cast(half2_t, b);
  return acc + (float)ha[0] * (float)hb[0] + (float)ha[1] * (float)hb[1];
#endif
}
__device__ __forceinline__ float dotq(v4u a, v4u b, float acc) {
  acc = dot2acc(a.x, b.x, acc);
  acc = dot2acc(a.y, b.y, acc);
  acc = dot2acc(a.z, b.z, acc);
  acc = dot2acc(a.w, b.w, acc);
  return acc;
}
__device__ __forceinline__ u32 pkf16(float a, float b) {
#if __has_builtin(__builtin_amdgcn_cvt_pkrtz)
  return __builtin_bit_cast(u32, __builtin_amdgcn_cvt_pkrtz(a, b));
#else
  half2_t h; h[0] = (_Float16)a; h[1] = (_Float16)b;
  return __builtin_bit_cast(u32, h);
#endif
}

// In-register shuffle reduction trees (value for index lane&(M-1)).
template<int M> struct TreeC {
  static __device__ __forceinline__ void run(float* a, int lane, int d) {
    const bool hi = (lane & d) != 0;
#pragma unroll
    for (int i = 0; i < M / 2; ++i) {
      float mine  = hi ? a[2 * i + 1] : a[2 * i];
      float yours = hi ? a[2 * i]     : a[2 * i + 1];
      a[i] = mine + __shfl_xor(yours, d, 64);
    }
    TreeC<M / 2>::run(a, lane, d << 1);
  }
};
template<> struct TreeC<1> {
  static __device__ __forceinline__ void run(float*, int, int) {}
};
template<int M>
__device__ __forceinline__ float tree_reduce(float* a, int lane) {
  TreeC<M>::run(a, lane, 1);
  float v = a[0];
#pragma unroll
  for (int d = M; d <= 32; d <<= 1) v += __shfl_xor(v, d, 64);
  return v;
}

// ---------------------------------------------------------------------------
// Master-aggregated group barrier (R4-proven flags; zero cache maintenance —
// data coherence comes from sc-flagged data ops, not fences).
// ---------------------------------------------------------------------------
__device__ __forceinline__ void xbar(u32* arrive, u32* go, int slot,
                                     unsigned gen, int tid) {
  __syncthreads();   // drains vmcnt: all comm stores at coherence point
  if (slot == 0) {
    if (tid >= 1 && tid < GWG)
      while (__hip_atomic_load(&arrive[tid * FPAD], __ATOMIC_RELAXED,
                               __HIP_MEMORY_SCOPE_AGENT) < gen) {}
    __syncthreads();
    if (tid == 0) mstore(go, gen);
  } else {
    if (tid == 0) {
      mstore(&arrive[slot * FPAD], gen);
      while (__hip_atomic_load(go, __ATOMIC_RELAXED,
                               __HIP_MEMORY_SCOPE_AGENT) < gen) {}
    }
  }
  __syncthreads();
}

// ---------------------------------------------------------------------------
// RMSNorm: one 256-thread WG per row of 512.
// ---------------------------------------------------------------------------
__global__ __launch_bounds__(256)
void rmsnorm_kernel(const float* __restrict__ x, const float* __restrict__ w,
                    float* __restrict__ y)
{
  __shared__ float redl[256];
  const long row = blockIdx.x;
  const int t = threadIdx.x;
  const float* xr = x + row * DD;
  float v0 = xr[t], v1 = xr[t + 256];
  redl[t] = v0 * v0 + v1 * v1;
  __syncthreads();
  for (int off = 128; off > 0; off >>= 1) {
    if (t < off) redl[t] += redl[t + off];
    __syncthreads();
  }
  float scale = rsqrtf(redl[0] * (1.0f / 512.0f) + 1e-5f);
  float* yr = y + row * DD;
  yr[t]       = v0 * scale * w[t];
  yr[t + 256] = v1 * scale * w[t + 256];
}

// ---------------------------------------------------------------------------
// fp32 tiled GEMM: C[M,N] = A[M,K] @ B[K,N] (+ bias[n]), all row-major.
// ---------------------------------------------------------------------------
__global__ __launch_bounds__(256)
void gemm_fp32(const float* __restrict__ A, const float* __restrict__ B,
               const float* __restrict__ bias, float* __restrict__ C,
               int M, int N, int K)
{
  __shared__ float As[16][68];
  __shared__ float Bs[16][64];
  const int t  = threadIdx.x;
  const int tx = t & 15, ty = t >> 4;
  const long m0 = (long)blockIdx.x * 64;
  const long n0 = (long)blockIdx.y * 64;
  const int ar = t >> 2, ac = (t & 3) * 4;
  const int bk = t >> 4, bn = (t & 15) * 4;
  float acc[4][4] = {{0.f}};

  for (int k0 = 0; k0 < K; k0 += 16) {
    float4 av = *(const float4*)(A + (m0 + ar) * K + k0 + ac);
    float4 bv = *(const float4*)(B + (long)(k0 + bk) * N + n0 + bn);
    As[ac + 0][ar] = av.x; As[ac + 1][ar] = av.y;
    As[ac + 2][ar] = av.z; As[ac + 3][ar] = av.w;
    *(float4*)&Bs[bk][bn] = bv;
    __syncthreads();
#pragma unroll
    for (int kk = 0; kk < 16; ++kk) {
      float4 a = *(const float4*)&As[kk][ty * 4];
      float4 b = *(const float4*)&Bs[kk][tx * 4];
      acc[0][0] = fmaf(a.x, b.x, acc[0][0]); acc[0][1] = fmaf(a.x, b.y, acc[0][1]);
      acc[0][2] = fmaf(a.x, b.z, acc[0][2]); acc[0][3] = fmaf(a.x, b.w, acc[0][3]);
      acc[1][0] = fmaf(a.y, b.x, acc[1][0]); acc[1][1] = fmaf(a.y, b.y, acc[1][1]);
      acc[1][2] = fmaf(a.y, b.z, acc[1][2]); acc[1][3] = fmaf(a.y, b.w, acc[1][3]);
      acc[2][0] = fmaf(a.z, b.x, acc[2][0]); acc[2][1] = fmaf(a.z, b.y, acc[2][1]);
      acc[2][2] = fmaf(a.z, b.z, acc[2][2]); acc[2][3] = fmaf(a.z, b.w, acc[2][3]);
      acc[3][0] = fmaf(a.w, b.x, acc[3][0]); acc[3][1] = fmaf(a.w, b.y, acc[3][1]);
      acc[3][2] = fmaf(a.w, b.z, acc[3][2]); acc[3][3] = fmaf(a.w, b.w, acc[3][3]);
    }
    __syncthreads();
  }
  float4 bb = make_float4(0.f, 0.f, 0.f, 0.f);
  if (bias) bb = *(const float4*)(bias + n0 + tx * 4);
#pragma unroll
  for (int i = 0; i < 4; ++i) {
    float4 o;
    o.x = acc[i][0] + bb.x; o.y = acc[i][1] + bb.y;
    o.z = acc[i][2] + bb.z; o.w = acc[i][3] + bb.w;
    *(float4*)(C + (m0 + ty * 4 + i) * N + n0 + tx * 4) = o;
  }
}

// ---------------------------------------------------------------------------
// Persistent scan: 512 WGs x 256 thr, 64 KB static LDS (f16 weight pairs).
// State for (row r=L>>1, col jz+2q+(L&1)) lives in lanes L<8 of wave q.
// ---------------------------------------------------------------------------
__global__ __launch_bounds__(256)
void scan_kernel(const float* __restrict__ gx,
                 const float* __restrict__ Whh, const float* __restrict__ bhh,
                 const float* __restrict__ loglam,
                 const float* __restrict__ kW1, const float* __restrict__ kb1,
                 const float* __restrict__ kW2, const float* __restrict__ kb2,
                 u32* __restrict__ cpk, u32* __restrict__ ipk,
                 u32* __restrict__ kpk, u32* __restrict__ flags,
                 float* __restrict__ hs)
{
  const int blk  = blockIdx.x;
  const int g    = blk & 7;         // group (rows 4g..4g+3)
  const int s    = blk >> 3;        // slot 0..63
  const int tid  = threadIdx.x;
  const int q    = tid >> 6;        // wave 0..3
  const int lane = tid & 63;
  const int jz   = s * 8;
  const int jm   = s * 24;

  __shared__ u32 wh[16 * 256];      // 16 KB: 8 z-cols + 8 m-cols, f16 pairs
  __shared__ u32 w1s[24 * 256];     // 24 KB
  __shared__ u32 w2s[8 * 768];      // 24 KB  (total 64 KB)

  // ---- one-time weight staging (fp32 -> f16 pairs; pair p <-> k=2p,2p+1) ----
  for (int idx = tid; idx < 16 * 256; idx += 256) {
    int c = idx >> 8, p = idx & 255;
    int gcol = (c < 8) ? (jz + c) : (512 + jz + (c - 8));
    wh[idx] = pkf16(Whh[(size_t)(2 * p) * G2H + gcol],
                    Whh[(size_t)(2 * p + 1) * G2H + gcol]);
  }
  for (int idx = tid; idx < 24 * 256; idx += 256) {
    int c = idx >> 8, p = idx & 255;
    w1s[idx] = pkf16(kW1[(size_t)(2 * p) * K3H + jm + c],
                     kW1[(size_t)(2 * p + 1) * K3H + jm + c]);
  }
  for (int idx = tid; idx < 8 * 768; idx += 256) {
    int c = idx / 768, p = idx - c * 768;
    w2s[idx] = pkf16(kW2[(size_t)(2 * p) * HH + jz + c],
                     kW2[(size_t)(2 * p + 1) * HH + jz + c]);
  }

  // per-lane constants (state mapping: r=lane>>1, ci=lane&1, valid lanes<8)
  const int colA = jz + 2 * q + (lane & 1);
  const float Ab   = 1.f - expf(loglam[colA]);
  const float bz   = bhh[colA];
  const float bm   = bhh[512 + colA];
  const float kb2c = kb2[colA];
  int kb1i = lane & 7; if (kb1i > 5) kb1i = 5;
  const float kb1v = kb1[jm + 6 * q + kb1i];

  const int r_st  = (lane >> 1) & 3;
  const int growst = 4 * g + r_st;
  const size_t hsoff = (size_t)growst * LSEQ * HH + colA;
  const size_t gxoff = (size_t)growst * LSEQ * G2H + colA;

  const u32* crow[4]; const u32* irow[4]; const u32* krow[4];
#pragma unroll
  for (int r = 0; r < 4; ++r) {
    crow[r] = cpk + (size_t)(4 * g + r) * 256 + lane * 4;
    irow[r] = ipk + (size_t)(4 * g + r) * 256 + lane * 4;
    krow[r] = kpk + (size_t)(4 * g + r) * 768 + lane * 4;
  }
  u32* arrive = flags + (size_t)g * (GWG + 1) * FPAD;
  u32* goflag = arrive + (size_t)GWG * FPAD;

  // zero this WG's initial c slice (pairs 4s..4s+3 of rows 4g..4g+3)
  if (tid < 16) {
    int r = tid >> 2, j = tid & 3;
    mstore(cpk + (size_t)(4 * g + r) * 256 + 4 * s + j, 0u);
  }
  unsigned gen = 1;
  xbar(arrive, goflag, s, gen, tid);   // zeros + LDS staging visible

  float A_own = 0.f, c_own = 0.f, M_own = 0.f, I_own = 0.f, s_own = 1.f;

  for (int it = 0; it <= LSEQ; ++it) {
    // gx prefetch (cached, read-once)
    float gxz = 0.f, gxm = 0.f;
    if (lane < 8 && it < LSEQ) {
      gxz = gx[gxoff + (size_t)it * G2H];
      gxm = gx[gxoff + (size_t)it * G2H + 512];
    }

    // ---- S1: sumsq(c) -> s ; g = h@W_hh ; innov ----
    v4u cv0, cv1, cv2, cv3;
    mload4(cv0, crow[0]); mload4(cv1, crow[1]);
    mload4(cv2, crow[2]); mload4(cv3, crow[3]);
    vmwait4(cv0, cv1, cv2, cv3);
    float a4[4] = { dotq(cv0, cv0, 0.f), dotq(cv1, cv1, 0.f),
                    dotq(cv2, cv2, 0.f), dotq(cv3, cv3, 0.f) };
    float a16[16];
#pragma unroll
    for (int t = 0; t < 4; ++t) {          // t<2: z col 2q+t ; t>=2: m col
      int col = (t < 2) ? (2 * q + t) : (8 + 2 * q + (t - 2));
      v4u wq = *(const v4u*)(wh + col * 256 + lane * 4);
      a16[0 * 4 + t] = dotq(cv0, wq, 0.f);
      a16[1 * 4 + t] = dotq(cv1, wq, 0.f);
      a16[2 * 4 + t] = dotq(cv2, wq, 0.f);
      a16[3 * 4 + t] = dotq(cv3, wq, 0.f);
    }
    float ssv = tree_reduce<4>(a4, lane);     // row = lane&3
    float g16 = tree_reduce<16>(a16, lane);   // (r=(lane&15)>>2, t=lane&3)
    float sq  = __shfl(ssv, r_st, 64);
    float s_loc = fminf(1.f, 10.f * rsqrtf(sq + 1e-6f));
    float gz = __shfl(g16, (r_st * 4 + (lane & 1)) & 63, 64);
    float gm = __shfl(g16, (r_st * 4 + 2 + (lane & 1)) & 63, 64);
    if (lane < 8 && it >= 1)
      hs[hsoff + (size_t)(it - 1) * HH] = s_loc * c_own;
    if (it == LSEQ) break;
    float gzv = gz * s_loc + gxz + bz;
    float gmv = gm * s_loc + gxm + bm;
    float Mv = tanhf(gmv);
    float iv = gzv - A_own * (s_loc * c_own) - Mv;
    if (lane < 8) { M_own = Mv; I_own = iv; s_own = s_loc; }
    float ivn = __shfl(iv, (lane + 1) & 63, 64);
    if (lane < 8 && !(lane & 1))
      mstore(ipk + (size_t)growst * 256 + 4 * s + q, pkf16(iv, ivn));
    ++gen; xbar(arrive, goflag, s, gen, tid);

    // ---- S2: kmid = gelu(innov @ kW1 + kb1), 6 cols x 4 rows ----
    v4u iv0, iv1, iv2, iv3;
    mload4(iv0, irow[0]); mload4(iv1, irow[1]);
    mload4(iv2, irow[2]); mload4(iv3, irow[3]);
    vmwait4(iv0, iv1, iv2, iv3);
    float a32[32];
#pragma unroll
    for (int i = 0; i < 32; ++i) a32[i] = 0.f;
#pragma unroll
    for (int cc = 0; cc < 6; ++cc) {
      v4u wq = *(const v4u*)(w1s + (6 * q + cc) * 256 + lane * 4);
      a32[0 * 8 + cc] = dotq(iv0, wq, 0.f);
      a32[1 * 8 + cc] = dotq(iv1, wq, 0.f);
      a32[2 * 8 + cc] = dotq(iv2, wq, 0.f);
      a32[3 * 8 + cc] = dotq(iv3, wq, 0.f);
    }
    float t32 = tree_reduce<32>(a32, lane);   // (r=(lane&31)>>3, cc=lane&7)
    float kvb = t32 + kb1v;
    float gl = 0.5f * kvb * (1.f + erff(kvb * 0.7071067811865476f));
    float gln = __shfl(gl, (lane + 1) & 63, 64);
    if (lane < 32 && !(lane & 1) && (lane & 7) < 6) {
      int rr = (lane >> 3) & 3, cc = lane & 7;
      mstore(kpk + (size_t)(4 * g + rr) * 768 + 12 * s + 3 * q + (cc >> 1),
             pkf16(gl, gln));
    }
    ++gen; xbar(arrive, goflag, s, gen, tid);

    // ---- S3: K = tanh(kmid @ kW2 + kb2)*0.5 ; c update ----
    v4u k00,k01,k02, k10,k11,k12, k20,k21,k22, k30,k31,k32;
    mload4(k00, krow[0]); mload4(k01, krow[0]+256); mload4(k02, krow[0]+512);
    mload4(k10, krow[1]); mload4(k11, krow[1]+256); mload4(k12, krow[1]+512);
    mload4(k20, krow[2]); mload4(k21, krow[2]+256); mload4(k22, krow[2]+512);
    mload4(k30, krow[3]); mload4(k31, krow[3]+256); mload4(k32, krow[3]+512);
    vmwait4(k00, k01, k02, k10);
    vmwait4(k11, k12, k20, k21);
    vmwait4(k22, k30, k31, k32);
    float a8[8];
#pragma unroll
    for (int ci = 0; ci < 2; ++ci) {
      const u32* wc = w2s + (2 * q + ci) * 768 + lane * 4;
      v4u wq0 = *(const v4u*)(wc);
      v4u wq1 = *(const v4u*)(wc + 256);
      v4u wq2 = *(const v4u*)(wc + 512);
      a8[0 * 2 + ci] = dotq(k02, wq2, dotq(k01, wq1, dotq(k00, wq0, 0.f)));
      a8[1 * 2 + ci] = dotq(k12, wq2, dotq(k11, wq1, dotq(k10, wq0, 0.f)));
      a8[2 * 2 + ci] = dotq(k22, wq2, dotq(k21, wq1, dotq(k20, wq0, 0.f)));
      a8[3 * 2 + ci] = dotq(k32, wq2, dotq(k31, wq1, dotq(k30, wq0, 0.f)));
    }
    float kr = tree_reduce<8>(a8, lane);   // (r=(lane&7)>>1, ci=lane&1) = state map
    float Kv = tanhf(kr + kb2c) * 0.5f;
    float An = Ab * (1.f - Kv * Kv);
    float cn = An * (s_own * c_own) + Kv * I_own + M_own;
    if (lane < 8) { A_own = An; c_own = cn; }
    float cnn = __shfl(cn, (lane + 1) & 63, 64);
    if (lane < 8 && !(lane & 1))
      mstore(cpk + (size_t)growst * 256 + 4 * s + q, pkf16(cn, cnn));
    ++gen; xbar(arrive, goflag, s, gen, tid);
  }
}

// ---------------------------------------------------------------------------
// Workspace layout (bytes):
//   [0, 32M)    xn (reused as hs)
//   [32M, 96M)  gx
//   [96M,128M)  xmid
//   [128M, ..)  cpk 32K | ipk 32K | kpk 96K | flags 33K
// ---------------------------------------------------------------------------
extern "C" void kernel_launch(void* const* d_in, const int* in_sizes, int n_in,
                              void* d_out, int out_size, void* d_ws, size_t ws_size,
                              hipStream_t stream) {
  const float* x      = (const float*)d_in[0];
  const float* norm_w = (const float*)d_in[1];
  const float* W_ih   = (const float*)d_in[2];
  const float* b_ih   = (const float*)d_in[3];
  const float* W_hh   = (const float*)d_in[4];
  const float* b_hh   = (const float*)d_in[5];
  const float* loglam = (const float*)d_in[6];
  const float* kW1    = (const float*)d_in[7];
  const float* kb1    = (const float*)d_in[8];
  const float* kW2    = (const float*)d_in[9];
  const float* kb2    = (const float*)d_in[10];
  const float* Wo     = (const float*)d_in[11];
  float* out = (float*)d_out;

  char* ws = (char*)d_ws;
  float* xn   = (float*)(ws);
  float* gxb  = (float*)(ws + (size_t)33554432);
  float* xmid = (float*)(ws + (size_t)100663296);
  u32* cpk   = (u32*)(ws + (size_t)134217728);
  u32* ipk   = cpk + 8192;
  u32* kpk   = ipk + 8192;
  u32* flags = kpk + 24576;
  float* hs = xn;

  const size_t flag_bytes = (size_t)NG * (GWG + 1) * FPAD * sizeof(u32);

  for (int l = 0; l < 2; ++l) {
    const float* xin = l ? (const float*)xmid : x;
    float* cout = l ? out : xmid;

    rmsnorm_kernel<<<BB * LSEQ, 256, 0, stream>>>(xin, norm_w, xn);

    gemm_fp32<<<dim3(256, 16), 256, 0, stream>>>(
        xn, W_ih + (size_t)l * DD * G2H, b_ih + (size_t)l * G2H, gxb,
        BB * LSEQ, G2H, DD);

    hipMemsetAsync(flags, 0, flag_bytes, stream);
    scan_kernel<<<NG * GWG, 256, 0, stream>>>(
        gxb,
        W_hh + (size_t)l * HH * G2H, b_hh + (size_t)l * G2H,
        loglam + (size_t)l * HH,
        kW1 + (size_t)l * HH * K3H, kb1 + (size_t)l * K3H,
        kW2 + (size_t)l * K3H * HH, kb2 + (size_t)l * HH,
        cpk, ipk, kpk, flags, hs);

    gemm_fp32<<<dim3(256, 8), 256, 0, stream>>>(
        hs, Wo + (size_t)l * HH * DD, nullptr, cout,
        BB * LSEQ, DD, HH);
  }
}